// Round 4
// baseline (550.157 us; speedup 1.0000x reference)
//
#include <hip/hip_runtime.h>
#include <hip/hip_bf16.h>

// MoBoAlignerAttention on MI355X — round 7.
// Change vs round 6 (phase1_a only): eliminate per-step global cp loads and
// thereby ALL per-step vmcnt waits. Theory: vmcnt is in-order; waiting on a
// prefetched cp load forces waiting on every a-store issued before it
// (~500cy L2 write-ack) -> per-step stall. Now cp is bulk-staged into LDS
// via global_load_lds (double-buffered 2x4 columns = 32KB), read back with a
// bank-conflict-free XOR swizzle (phys = w ^ (((w>>5)&3)<<2), inverse-
// pre-swizzled global source per both-sides-or-neither rule), and the only
// vmcnt wait is one s_waitcnt vmcnt(32) per 4 steps whose count excludes the
// trailing stores. cp registers ping-pong 1 step ahead (X/Y named sets).
// Window/store arithmetic is bit-identical to round 6.
//
// Pipeline:
//  conv_bf16   : mel f32 -> melh bf16 [n][j][d]
//  conv_encT   : enc f32 -> ench bf16 [n][k][d]  +  encT bf16 [n][d][k]
//  gemm_mfma   : scores = melh @ ench^T / sqrt(512)         (bf16 MFMA)
//  gen_T       : JAX Threefry-2x32 (partitionable) uniform
//  softmax_rows: s_alignment -> d_out
//  cond_prob2  : cp = e / (window_19(e)+1e-8), k-major cpT
//  phase1_a    : a_k[j] = sum_{t=j-20..j-2} a_{k-1}[t]*cp_{k-1}[t]  (1 wave/n)
//  phase2_B    : B[j,k] = sum_{d=2..19} a[j-d,k]*W_{20-d}(j,k)
//  transpose_B : BT -> d_out B slot (f32) + Bh bf16 [n][j][k]
//  gemm_mfma   : att = Bh @ encT^T                          (bf16 MFMA)

#define NB 32
#define TD 1024
#define TE 384
#define DM 512

typedef __attribute__((ext_vector_type(8))) short bf16x8;
typedef __attribute__((ext_vector_type(4))) float f32x4;

// f32 -> bf16 round-to-nearest-even
__device__ __forceinline__ ushort f2bf(float f) {
  unsigned u = __float_as_uint(f);
  return (ushort)((u + 0x7FFFu + ((u >> 16) & 1u)) >> 16);
}

// ---------------------------------------------------------------- threefry
__device__ __forceinline__ void tf_round(unsigned &x0, unsigned &x1, int r) {
  x0 += x1;
  x1 = (x1 << r) | (x1 >> (32 - r));
  x1 ^= x0;
}

__device__ __forceinline__ void threefry2x32(unsigned c0, unsigned c1,
                                             unsigned &o0, unsigned &o1) {
  const unsigned k0 = 0u, k1 = 1234u;
  const unsigned k2 = 0u ^ 1234u ^ 0x1BD11BDAu;
  unsigned x0 = c0 + k0, x1 = c1 + k1;
  tf_round(x0, x1, 13); tf_round(x0, x1, 15); tf_round(x0, x1, 26); tf_round(x0, x1, 6);
  x0 += k1; x1 += k2 + 1u;
  tf_round(x0, x1, 17); tf_round(x0, x1, 29); tf_round(x0, x1, 16); tf_round(x0, x1, 24);
  x0 += k2; x1 += k0 + 2u;
  tf_round(x0, x1, 13); tf_round(x0, x1, 15); tf_round(x0, x1, 26); tf_round(x0, x1, 6);
  x0 += k0; x1 += k1 + 3u;
  tf_round(x0, x1, 17); tf_round(x0, x1, 29); tf_round(x0, x1, 16); tf_round(x0, x1, 24);
  x0 += k1; x1 += k2 + 4u;
  tf_round(x0, x1, 13); tf_round(x0, x1, 15); tf_round(x0, x1, 26); tf_round(x0, x1, 6);
  x0 += k2; x1 += k0 + 5u;
  o0 = x0; o1 = x1;
}

__device__ __forceinline__ float tf_uniform(unsigned bits) {
  return __uint_as_float((bits >> 9) | 0x3F800000u) - 1.0f;
}

__global__ __launch_bounds__(256) void gen_T(float *__restrict__ Tbuf) {
  int i = blockIdx.x * blockDim.x + threadIdx.x;  // 0..12287
  if (i >= NB * TE) return;
  unsigned o0, o1;
  threefry2x32(0u, (unsigned)i, o0, o1);
  Tbuf[i] = tf_uniform(o0 ^ o1) + 0.5f;  // T = u*(1.5-0.5)+0.5
}

// ---------------------------------------------------------------- f32 -> bf16 (8 elems/thread)
__global__ __launch_bounds__(256) void conv_bf16(const float *__restrict__ src,
                                                 ushort *__restrict__ dst) {
  const size_t i = ((size_t)blockIdx.x * 256 + threadIdx.x) * 8;
  float4 a = *(const float4 *)(src + i);
  float4 b = *(const float4 *)(src + i + 4);
  uint4 o;
  o.x = (unsigned)f2bf(a.x) | ((unsigned)f2bf(a.y) << 16);
  o.y = (unsigned)f2bf(a.z) | ((unsigned)f2bf(a.w) << 16);
  o.z = (unsigned)f2bf(b.x) | ((unsigned)f2bf(b.y) << 16);
  o.w = (unsigned)f2bf(b.z) | ((unsigned)f2bf(b.w) << 16);
  *(uint4 *)(dst + i) = o;
}

// ---------------------------------------------------------------- enc -> ench + encT
__global__ __launch_bounds__(256) void conv_encT(const float *__restrict__ enc,
                                                 ushort *__restrict__ ench,
                                                 ushort *__restrict__ encT) {
  const int n = blockIdx.z;
  const int d0 = blockIdx.x * 32;
  const int k0 = blockIdx.y * 32;
  __shared__ ushort t[32][33];
  const int row = threadIdx.x >> 3;      // k within tile
  const int c4 = (threadIdx.x & 7) * 4;  // d within tile
  float4 v = *(const float4 *)(enc + ((size_t)n * TE + k0 + row) * DM + d0 + c4);
  ushort4 e;
  e.x = f2bf(v.x); e.y = f2bf(v.y); e.z = f2bf(v.z); e.w = f2bf(v.w);
  t[row][c4 + 0] = e.x; t[row][c4 + 1] = e.y;
  t[row][c4 + 2] = e.z; t[row][c4 + 3] = e.w;
  *(ushort4 *)(ench + ((size_t)n * TE + k0 + row) * DM + d0 + c4) = e;
  __syncthreads();
  const int dr = threadIdx.x >> 3;       // d within tile
  const int kc = (threadIdx.x & 7) * 4;  // k within tile
  ushort4 o;
  o.x = t[kc + 0][dr]; o.y = t[kc + 1][dr];
  o.z = t[kc + 2][dr]; o.w = t[kc + 3][dr];
  *(ushort4 *)(encT + ((size_t)n * DM + d0 + dr) * TE + k0 + kc) = o;
}

// ---------------------------------------------------------------- bf16 MFMA GEMM
// C[m][n] = scale * sum_k A[m][k]*B[n][k]   (both operands K-contiguous)
// 128x128 tile, 4 waves (2x2), each wave 4x4 16x16x32 MFMA tiles, BK=32.
__global__ __launch_bounds__(256) void gemm_bf16_mfma(
    const ushort *__restrict__ Ag, const ushort *__restrict__ Bg,
    float *__restrict__ Cg, int K, int N, size_t sA, size_t sB, size_t sC,
    float scale) {
  const int nb = blockIdx.z;
  const int n0 = blockIdx.x * 128;
  const int m0 = blockIdx.y * 128;
  const int tid = threadIdx.x;
  const int wave = tid >> 6, lane = tid & 63;
  const int wm = (wave >> 1) * 64, wn = (wave & 1) * 64;
  const int fr = lane & 15, quad = lane >> 4;
  const ushort *A = Ag + nb * sA + (size_t)m0 * K;
  const ushort *B = Bg + nb * sB + (size_t)n0 * K;
  __shared__ ushort As[128 * 32];
  __shared__ ushort Bs[128 * 32];
  f32x4 acc[4][4];
#pragma unroll
  for (int i = 0; i < 4; ++i)
#pragma unroll
    for (int c = 0; c < 4; ++c) acc[i][c] = (f32x4){0.f, 0.f, 0.f, 0.f};

  const int srow = tid >> 1;        // 0..127
  const int scol = (tid & 1) * 16;  // 0 or 16 (ushort offset)
  for (int kb = 0; kb < K; kb += 32) {
    uint4 av0 = *(const uint4 *)(A + (size_t)srow * K + kb + scol);
    uint4 av1 = *(const uint4 *)(A + (size_t)srow * K + kb + scol + 8);
    uint4 bv0 = *(const uint4 *)(B + (size_t)srow * K + kb + scol);
    uint4 bv1 = *(const uint4 *)(B + (size_t)srow * K + kb + scol + 8);
    __syncthreads();
    *(uint4 *)(&As[srow * 32 + scol]) = av0;
    *(uint4 *)(&As[srow * 32 + scol + 8]) = av1;
    *(uint4 *)(&Bs[srow * 32 + scol]) = bv0;
    *(uint4 *)(&Bs[srow * 32 + scol + 8]) = bv1;
    __syncthreads();
    bf16x8 af[4], bfv[4];
#pragma unroll
    for (int i = 0; i < 4; ++i)
      af[i] = *(const bf16x8 *)(&As[(wm + i * 16 + fr) * 32 + quad * 8]);
#pragma unroll
    for (int c = 0; c < 4; ++c)
      bfv[c] = *(const bf16x8 *)(&Bs[(wn + c * 16 + fr) * 32 + quad * 8]);
#pragma unroll
    for (int i = 0; i < 4; ++i)
#pragma unroll
      for (int c = 0; c < 4; ++c)
        acc[i][c] = __builtin_amdgcn_mfma_f32_16x16x32_bf16(af[i], bfv[c],
                                                            acc[i][c], 0, 0, 0);
  }
  float *Cb = Cg + nb * sC;
#pragma unroll
  for (int i = 0; i < 4; ++i)
#pragma unroll
    for (int c = 0; c < 4; ++c)
#pragma unroll
      for (int r = 0; r < 4; ++r)
        Cb[(size_t)(m0 + wm + i * 16 + quad * 4 + r) * N + n0 + wn + c * 16 + fr] =
            acc[i][c][r] * scale;
}

// ---------------------------------------------------------------- softmax
__global__ __launch_bounds__(64) void softmax_rows(
    const float *__restrict__ scores, float *__restrict__ out1) {
  const int row = blockIdx.x;  // n*TD + j
  const int n = row >> 10;
  const int j = row & 1023;
  const int tid = threadIdx.x;
  const float *s = scores + (size_t)row * TE;
  float v[6];
#pragma unroll
  for (int i = 0; i < 6; ++i) v[i] = s[tid + 64 * i];
  float m = v[0];
#pragma unroll
  for (int i = 1; i < 6; ++i) m = fmaxf(m, v[i]);
#pragma unroll
  for (int off = 32; off; off >>= 1) m = fmaxf(m, __shfl_xor(m, off));
  float e[6], sum = 0.f;
#pragma unroll
  for (int i = 0; i < 6; ++i) { e[i] = __expf(v[i] - m); sum += e[i]; }
#pragma unroll
  for (int off = 32; off; off >>= 1) sum += __shfl_xor(sum, off);
  const float r = 1.0f / sum;
  float *dst = out1 + (size_t)n * (2 * TD * TE) + (size_t)j * TE;
#pragma unroll
  for (int i = 0; i < 6; ++i) dst[tid + 64 * i] = e[i] * r;
}

// ---------------------------------------------------------------- cond_prob (parallel)
__global__ __launch_bounds__(256) void cond_prob2(
    const float *__restrict__ scores, const float *__restrict__ Tbuf,
    float *__restrict__ cpT) {
  const int n = blockIdx.z;
  const int j0 = blockIdx.y * 64;
  const int k0 = blockIdx.x * 64;
  const int tid = threadIdx.x;
  __shared__ float eL[82][65];

  {
    const int c4 = (tid & 15) * 4;
    const int r0 = tid >> 4;  // 0..15
    float4 tv = *(const float4 *)(Tbuf + n * TE + k0 + c4);
    const float it0 = 1.0f / tv.x, it1 = 1.0f / tv.y, it2 = 1.0f / tv.z,
                it3 = 1.0f / tv.w;
#pragma unroll
    for (int p = 0; p < 6; ++p) {
      const int r = r0 + p * 16;
      if (r < 82) {
        const int j = j0 + r;
        float4 s;
        if (j < TD) {
          s = *(const float4 *)(scores + ((size_t)n * TD + j) * TE + k0 + c4);
          s.x = __expf(s.x * it0); s.y = __expf(s.y * it1);
          s.z = __expf(s.z * it2); s.w = __expf(s.w * it3);
        } else {
          s = make_float4(0.f, 0.f, 0.f, 0.f);
        }
        eL[r][c4 + 0] = s.x; eL[r][c4 + 1] = s.y;
        eL[r][c4 + 2] = s.z; eL[r][c4 + 3] = s.w;
      }
    }
  }
  __syncthreads();

  const int k = tid & 63;
  const int jl0 = (tid >> 6) * 16;
  float e_r[35];
#pragma unroll
  for (int t = 0; t < 35; ++t) e_r[t] = eL[jl0 + t][k];
  float win = 0.f;
#pragma unroll
  for (int t = 15; t <= 33; ++t) win += e_r[t];
  float cp[16];
#pragma unroll
  for (int jl = 15; jl >= 0; --jl) {
    cp[jl] = e_r[jl] / (win + 1e-8f);
    if (jl > 0) win += e_r[jl - 1] - e_r[jl + 18];
  }
  float *dst = cpT + ((size_t)n * TE + k0 + k) * TD + j0 + jl0;
#pragma unroll
  for (int q = 0; q < 4; ++q)
    *(float4 *)(dst + q * 4) =
        make_float4(cp[q * 4], cp[q * 4 + 1], cp[q * 4 + 2], cp[q * 4 + 3]);
}

// ---------------------------------------------------------------- phase 1 (a scan)
// Single wave per batch n, 16 j per lane, 384 serial k-steps.
//  * q-exchange through qbuf (pad-swizzled, conflict-free), compiler fences
//    only (same-wave DS pipe is in-order) — as round 6.
//  * cp comes from an LDS double buffer (2 x 4 columns x 4KB = 32KB) bulk-
//    staged with global_load_lds; one s_waitcnt vmcnt(32) per 4 steps. The
//    count (16 a-stores of prev group + 16 glds just issued) excludes all
//    trailing stores -> stores are never waited on inside the loop.
//  * staged buffer read with XOR swizzle phys = w ^ (((w>>5)&3)<<2); the
//    glds global SOURCE is inverse-pre-swizzled (involution; permutes 16B
//    chunks within 64B lines -> still fully coalesced).
#define P1PH(J) ((J) + (((J) >> 4) << 2))

// cp register prefetch from staged LDS (phys-swizzled lane offsets rb0..rb3)
#define P1_LOADCP(D0, D1, D2, D3, WOFF)                                       \
  do {                                                                        \
    D0 = *(const float4 *)(cpl + (WOFF) + rb0);                               \
    D1 = *(const float4 *)(cpl + (WOFF) + rb1);                               \
    D2 = *(const float4 *)(cpl + (WOFF) + rb2);                               \
    D3 = *(const float4 *)(cpl + (WOFF) + rb3);                               \
  } while (0)

#define P1_CORE(CQ0, CQ1, CQ2, CQ3, CPLOAD, kk)                               \
  {                                                                           \
    float4 q0 = make_float4(a[0] * CQ0.x, a[1] * CQ0.y,                       \
                            a[2] * CQ0.z, a[3] * CQ0.w);                      \
    float4 q1 = make_float4(a[4] * CQ1.x, a[5] * CQ1.y,                       \
                            a[6] * CQ1.z, a[7] * CQ1.w);                      \
    float4 q2 = make_float4(a[8] * CQ2.x, a[9] * CQ2.y,                       \
                            a[10] * CQ2.z, a[11] * CQ2.w);                    \
    float4 q3 = make_float4(a[12] * CQ3.x, a[13] * CQ3.y,                     \
                            a[14] * CQ3.z, a[15] * CQ3.w);                    \
    *(float4 *)(w01p) = q0;                                                   \
    *(float4 *)(w01p + 4) = q1;                                               \
    *(float4 *)(w23p) = q2;                                                   \
    *(float4 *)(w23p + 4) = q3;                                               \
    asm volatile("" ::: "memory"); /* order writes before reads (compiler) */ \
    float4 h1 = *(const float4 *)(rdA);                                       \
    float4 h2 = *(const float4 *)(rdA + 4);                                   \
    float4 h3 = *(const float4 *)(rdA + 8);                                   \
    float4 h4 = *(const float4 *)(rdB);                                       \
    float4 h5 = *(const float4 *)(rdB + 4);                                   \
    CPLOAD; /* next step's cp; latency hides under window compute */          \
    asm volatile("" ::: "memory"); /* order reads before next-step writes */  \
    float w[38];                                                              \
    w[4] = h1.x;  w[5] = h1.y;  w[6] = h1.z;  w[7] = h1.w;                    \
    w[8] = h2.x;  w[9] = h2.y;  w[10] = h2.z; w[11] = h2.w;                   \
    w[12] = h3.x; w[13] = h3.y; w[14] = h3.z; w[15] = h3.w;                   \
    w[16] = h4.x; w[17] = h4.y; w[18] = h4.z; w[19] = h4.w;                   \
    w[20] = h5.x; w[21] = h5.y; w[22] = h5.z; w[23] = h5.w;                   \
    w[24] = q0.x; w[25] = q0.y; w[26] = q0.z; w[27] = q0.w;                   \
    w[28] = q1.x; w[29] = q1.y; w[30] = q1.z; w[31] = q1.w;                   \
    w[32] = q2.x; w[33] = q2.y; w[34] = q2.z; w[35] = q2.w;                   \
    w[36] = q3.x; w[37] = q3.y;                                               \
    /* window for j=j0+i is sum w[i+4 .. i+22]; two balanced trees + slides */\
    float t0 = w[4] + w[5], t1 = w[6] + w[7], t2 = w[8] + w[9];               \
    float t3 = w[10] + w[11], t4 = w[12] + w[13], t5 = w[14] + w[15];         \
    float t6 = w[16] + w[17], t7 = w[18] + w[19], t8 = w[20] + w[21];         \
    float s0 = (((t0 + t1) + (t2 + t3)) + ((t4 + t5) + (t6 + t7))) +          \
               (t8 + w[22]);                                                  \
    a[0] = s0;                                                                \
    s0 += w[23] - w[4];  a[1] = s0;                                           \
    s0 += w[24] - w[5];  a[2] = s0;                                           \
    s0 += w[25] - w[6];  a[3] = s0;                                           \
    s0 += w[26] - w[7];  a[4] = s0;                                           \
    s0 += w[27] - w[8];  a[5] = s0;                                           \
    s0 += w[28] - w[9];  a[6] = s0;                                           \
    s0 += w[29] - w[10]; a[7] = s0;                                           \
    float u4 = w[20] + w[21], u5 = w[22] + w[23], u6 = w[24] + w[25];         \
    float u7 = w[26] + w[27], u8 = w[28] + w[29];                             \
    float s1 = (((t4 + t5) + (t6 + t7)) + ((u4 + u5) + (u6 + u7))) +          \
               (u8 + w[30]);                                                  \
    a[8] = s1;                                                                \
    s1 += w[31] - w[12]; a[9] = s1;                                           \
    s1 += w[32] - w[13]; a[10] = s1;                                          \
    s1 += w[33] - w[14]; a[11] = s1;                                          \
    s1 += w[34] - w[15]; a[12] = s1;                                          \
    s1 += w[35] - w[16]; a[13] = s1;                                          \
    s1 += w[36] - w[17]; a[14] = s1;                                          \
    s1 += w[37] - w[18]; a[15] = s1;                                          \
    float *ao = an + (size_t)(kk)*TD + j0;                                    \
    *(float4 *)(ao) = make_float4(a[0], a[1], a[2], a[3]);                    \
    *(float4 *)(ao + 4) = make_float4(a[4], a[5], a[6], a[7]);                \
    *(float4 *)(ao + 8) = make_float4(a[8], a[9], a[10], a[11]);              \
    *(float4 *)(ao + 12) = make_float4(a[12], a[13], a[14], a[15]);           \
  }

// stage 4 cp columns (for steps 4*gi .. 4*gi+3; slot t holds column
// max(4*gi+t-1, 0) clamped to TE-1) into an LDS buffer via global_load_lds.
// Dest is linear (wave-uniform base + lane*16); source is inverse-swizzled.
__device__ __forceinline__ void p1_stage(const float *__restrict__ cpn,
                                         float *buf, int gi, int lane) {
  const int lsw = 4 * (lane ^ ((lane >> 3) & 3));  // pre-swizzled source word
#pragma unroll
  for (int t = 0; t < 4; ++t) {
    const int s = 4 * gi + t;
    int col = (s > 0) ? (s - 1) : 0;
    if (col > TE - 1) col = TE - 1;  // only hit by the wasted last stage
    const float *src = cpn + (size_t)col * TD + lsw;
#pragma unroll
    for (int i = 0; i < 4; ++i) {
      __builtin_amdgcn_global_load_lds(
          (const __attribute__((address_space(1))) unsigned int *)(src + i * 256),
          (__attribute__((address_space(3))) unsigned int *)(buf + t * 1024 + i * 256),
          16, 0, 0);
    }
  }
}

__global__ __launch_bounds__(64) void phase1_a(
    const float *__restrict__ cpT, float *__restrict__ aT) {
  const int n = blockIdx.x;
  const int L = threadIdx.x;  // 0..63, one wave
  const int j0 = L * 16;
  __shared__ __align__(16) float qbuf[1320];  // 66 groups * 20 floats
  __shared__ __align__(16) float cpl[8192];   // 2 buffers x 4 cols x 1024

  // zero the 24-float logical pad (j in [-24,-1] -> J in [0,24))
  if (L < 24) qbuf[P1PH(L)] = 0.f;

  const float *cpn = cpT + (size_t)n * TE * TD;
  float *an = aT + (size_t)n * TE * TD;

  // qbuf lane pointers (b128-aligned, conflict-free under +4/16 pad swizzle)
  float *w01p = &qbuf[P1PH(j0 + 24)];
  float *w23p = &qbuf[P1PH(j0 + 32)];
  const float *rdA = &qbuf[P1PH(j0) + 4];
  const float *rdB = &qbuf[P1PH(j0 + 16)];

  // cp staged-buffer lane read offsets: logical words 16L+4r -> phys
  // 16L + 4*(r ^ m), m = (L>>1)&3 (uniform 8 words/bank across the wave)
  const int m_ = (L >> 1) & 3;
  const int rb0 = 16 * L + 4 * (0 ^ m_);
  const int rb1 = 16 * L + 4 * (1 ^ m_);
  const int rb2 = 16 * L + 4 * (2 ^ m_);
  const int rb3 = 16 * L + 4 * (3 ^ m_);

  float a[16];
#pragma unroll
  for (int i = 0; i < 16; ++i) a[i] = 0.f;
  if (L == 0) a[0] = 1.f;

  // prologue: stage group 0 into buffer 0 and drain (no stores yet)
  p1_stage(cpn, cpl, 0, L);
  asm volatile("s_waitcnt vmcnt(0)" ::: "memory");

  float4 cpX0, cpX1, cpX2, cpX3, cpY0, cpY1, cpY2, cpY3;

#pragma unroll 1
  for (int g = 0; g < 96; ++g) {  // 96 groups x 4 steps = TE
    const int ab = (g & 1) << 12;   // active buffer word offset
    const int bb = 4096 - ab;       // back buffer (staged for group g+1)
    p1_stage(cpn, cpl + bb, g + 1, L);  // 16 glds (g=95: wasted, clamped)
    // wait for stage(g) (issued at group g-1 top): ops after it =
    // 16 a-stores of group g-1 + the 16 glds just issued = 32.
    asm volatile("s_waitcnt vmcnt(32)" ::: "memory");
    P1_LOADCP(cpX0, cpX1, cpX2, cpX3, ab);  // cp for step 4g (slot 0)
    const int kk = 4 * g;
    P1_CORE(cpX0, cpX1, cpX2, cpX3,
            P1_LOADCP(cpY0, cpY1, cpY2, cpY3, ab + 1024), kk);
    P1_CORE(cpY0, cpY1, cpY2, cpY3,
            P1_LOADCP(cpX0, cpX1, cpX2, cpX3, ab + 2048), kk + 1);
    P1_CORE(cpX0, cpX1, cpX2, cpX3,
            P1_LOADCP(cpY0, cpY1, cpY2, cpY3, ab + 3072), kk + 2);
    P1_CORE(cpY0, cpY1, cpY2, cpY3, (void)0, kk + 3);
  }
}

// ---------------------------------------------------------------- phase 2 (B)
__global__ __launch_bounds__(256) void phase2_B(
    const float *__restrict__ cpT, const float *__restrict__ aT,
    float *__restrict__ BT) {
  const int k = blockIdx.x;
  const int n = blockIdx.y;
  const int tid = threadIdx.x;
  const float *cpc = cpT + ((size_t)n * TE + k) * TD;
  const float *ac = aT + ((size_t)n * TE + k) * TD;
  __shared__ float a_l[20 + TD];
  __shared__ float cp_l[TD + 24];
  float4 av = *(const float4 *)(ac + tid * 4);
  *(float4 *)(&a_l[20 + tid * 4]) = av;
  float4 cv = *(const float4 *)(cpc + tid * 4);
  if (tid == 255) cv.w = 0.f;  // cp[1023] never contributes (clamp rule)
  *(float4 *)(&cp_l[tid * 4]) = cv;
  if (tid < 20) a_l[tid] = 0.f;
  if (tid < 24) cp_l[TD + tid] = 0.f;
  __syncthreads();
  const int j0 = tid * 4;
  float ar[21], cpr[21];
#pragma unroll
  for (int t = 0; t < 21; ++t) ar[t] = a_l[20 + j0 - 19 + t];
#pragma unroll
  for (int t = 0; t < 21; ++t) cpr[t] = cp_l[j0 + t];
  float Bo[4];
#pragma unroll
  for (int i = 0; i < 4; ++i) {
    float W = 0.f, acc2 = 0.f;
#pragma unroll
    for (int d = 19; d >= 2; --d) {
      W += cpr[i + 19 - d];
      acc2 = fmaf(ar[19 + i - d], W, acc2);
    }
    Bo[i] = acc2;
  }
  *(float4 *)(BT + ((size_t)n * TE + k) * TD + j0) =
      make_float4(Bo[0], Bo[1], Bo[2], Bo[3]);
}

// ---------------------------------------------------------------- transpose (+ bf16 copy)
__global__ __launch_bounds__(256) void transpose_B(
    const float *__restrict__ BT, float *__restrict__ out1,
    ushort *__restrict__ Bh) {
  __shared__ float tile[32][33];
  const int n = blockIdx.z;
  const int k0 = blockIdx.x * 32;
  const int j0 = blockIdx.y * 32;
  const int tx = threadIdx.x & 31;
  const int ty = threadIdx.x >> 5;  // 0..7
  const float *src = BT + (size_t)n * TE * TD;
#pragma unroll
  for (int r = 0; r < 4; ++r) {
    const int kk = ty + r * 8;
    tile[kk][tx] = src[(size_t)(k0 + kk) * TD + j0 + tx];
  }
  __syncthreads();
  float *dst = out1 + (size_t)n * (2 * TD * TE) + (size_t)TD * TE;
#pragma unroll
  for (int r = 0; r < 4; ++r) {
    const int jj = ty + r * 8;
    const float val = tile[tx][jj];
    dst[(size_t)(j0 + jj) * TE + k0 + tx] = val;
    Bh[((size_t)n * TD + j0 + jj) * TE + k0 + tx] = f2bf(val);
  }
}

// ---------------------------------------------------------------- launch
extern "C" void kernel_launch(void *const *d_in, const int *in_sizes, int n_in,
                              void *d_out, int out_size, void *d_ws,
                              size_t ws_size, hipStream_t stream) {
  (void)in_sizes; (void)n_in; (void)out_size; (void)ws_size;
  const float *enc = (const float *)d_in[0];  // [32][384][512]
  const float *mel = (const float *)d_in[1];  // [32][1024][512]
  float *out = (float *)d_out;
  float *out0 = out;                         // att_out [32][1024][512]
  float *out1 = out + (size_t)NB * TD * DM;  // stacked [32][2][1024][384]

  const size_t SZ = (size_t)NB * TD * TE;    // 12,582,912 floats
  float *ws = (float *)d_ws;
  float *ws_scores = ws;       // scores [n][j][k]; later BT
  float *ws_cpT = ws + SZ;     // cond_prob [n][k][j] (holds ench+melh before)
  float *ws_aT = ws + 2 * SZ;  // a [n][k][j] (holds Bh after phase2)
  float *ws_T = ws + 3 * SZ;   // T [n][k]
  ushort *encTb = (ushort *)(ws + 3 * SZ + NB * TE);  // encT bf16 [n][d][k]
  ushort *ench = (ushort *)ws_cpT;                    // bf16 [n][k][d]
  ushort *melh = (ushort *)ws_cpT + (size_t)NB * TE * DM;  // bf16 [n][j][d]
  ushort *Bh = (ushort *)ws_aT;                       // bf16 [n][j][k]
  float *ws_BT = ws_scores;

  conv_bf16<<<(NB * TD * DM) / (256 * 8), 256, 0, stream>>>(mel, melh);
  conv_encT<<<dim3(DM / 32, TE / 32, NB), 256, 0, stream>>>(enc, ench, encTb);
  gen_T<<<48, 256, 0, stream>>>(ws_T);
  gemm_bf16_mfma<<<dim3(TE / 128, TD / 128, NB), 256, 0, stream>>>(
      melh, ench, ws_scores, DM, TE, (size_t)TD * DM, (size_t)TE * DM,
      (size_t)TD * TE, 0.0441941738241592f);
  softmax_rows<<<NB * TD, 64, 0, stream>>>(ws_scores, out1);
  cond_prob2<<<dim3(TE / 64, TD / 64, NB), 256, 0, stream>>>(ws_scores, ws_T, ws_cpT);
  phase1_a<<<NB, 64, 0, stream>>>(ws_cpT, ws_aT);
  phase2_B<<<dim3(TE, NB), 256, 0, stream>>>(ws_cpT, ws_aT, ws_BT);
  transpose_B<<<dim3(TE / 32, TD / 32, NB), 256, 0, stream>>>(ws_BT, out1, Bh);
  gemm_bf16_mfma<<<dim3(DM / 128, TD / 128, NB), 256, 0, stream>>>(
      Bh, encTb, out0, TE, DM, (size_t)TD * TE, (size_t)DM * TE,
      (size_t)TD * DM, 1.0f);
}

// Round 5
// 517.577 us; speedup vs baseline: 1.0629x; 1.0629x over previous
//
#include <hip/hip_runtime.h>
#include <hip/hip_bf16.h>

// MoBoAlignerAttention on MI355X — round 8.
// Changes vs round 7:
//  * phase1_a REVERTED to round 6 (best measured: 121.8 µs, 0 conflicts).
//    Round 7's LDS-staged cp regressed (160.9 µs): it moved cp into the
//    per-step critical path (13 DS ops/step) and its cpl swizzle conflicted.
//  * gemm_bf16_mfma: register staging replaced by global_load_lds width=16
//    (m97 pattern: 4 glds/wave per K-step, 16 rows per 1KiB instruction,
//    per-lane global src + wave-uniform LDS base). Removes the VGPR
//    round-trip and staging address VALU.
//  * softmax_rows: float2 loads/stores (8B/lane).
//
// Pipeline:
//  conv_bf16   : mel f32 -> melh bf16 [n][j][d]
//  conv_encT   : enc f32 -> ench bf16 [n][k][d]  +  encT bf16 [n][d][k]
//  gemm_mfma   : scores = melh @ ench^T / sqrt(512)         (bf16 MFMA)
//  gen_T       : JAX Threefry-2x32 (partitionable) uniform
//  softmax_rows: s_alignment -> d_out
//  cond_prob2  : cp = e / (window_19(e)+1e-8), k-major cpT
//  phase1_a    : a_k[j] = sum_{t=j-20..j-2} a_{k-1}[t]*cp_{k-1}[t]  (1 wave/n)
//  phase2_B    : B[j,k] = sum_{d=2..19} a[j-d,k]*W_{20-d}(j,k)
//  transpose_B : BT -> d_out B slot (f32) + Bh bf16 [n][j][k]
//  gemm_mfma   : att = Bh @ encT^T                          (bf16 MFMA)

#define NB 32
#define TD 1024
#define TE 384
#define DM 512

typedef __attribute__((ext_vector_type(8))) short bf16x8;
typedef __attribute__((ext_vector_type(4))) float f32x4;

#define GLDS16(g, l)                                                          \
  __builtin_amdgcn_global_load_lds(                                           \
      (const __attribute__((address_space(1))) unsigned int *)(g),            \
      (__attribute__((address_space(3))) unsigned int *)(l), 16, 0, 0)

// f32 -> bf16 round-to-nearest-even
__device__ __forceinline__ ushort f2bf(float f) {
  unsigned u = __float_as_uint(f);
  return (ushort)((u + 0x7FFFu + ((u >> 16) & 1u)) >> 16);
}

// ---------------------------------------------------------------- threefry
__device__ __forceinline__ void tf_round(unsigned &x0, unsigned &x1, int r) {
  x0 += x1;
  x1 = (x1 << r) | (x1 >> (32 - r));
  x1 ^= x0;
}

__device__ __forceinline__ void threefry2x32(unsigned c0, unsigned c1,
                                             unsigned &o0, unsigned &o1) {
  const unsigned k0 = 0u, k1 = 1234u;
  const unsigned k2 = 0u ^ 1234u ^ 0x1BD11BDAu;
  unsigned x0 = c0 + k0, x1 = c1 + k1;
  tf_round(x0, x1, 13); tf_round(x0, x1, 15); tf_round(x0, x1, 26); tf_round(x0, x1, 6);
  x0 += k1; x1 += k2 + 1u;
  tf_round(x0, x1, 17); tf_round(x0, x1, 29); tf_round(x0, x1, 16); tf_round(x0, x1, 24);
  x0 += k2; x1 += k0 + 2u;
  tf_round(x0, x1, 13); tf_round(x0, x1, 15); tf_round(x0, x1, 26); tf_round(x0, x1, 6);
  x0 += k0; x1 += k1 + 3u;
  tf_round(x0, x1, 17); tf_round(x0, x1, 29); tf_round(x0, x1, 16); tf_round(x0, x1, 24);
  x0 += k1; x1 += k2 + 4u;
  tf_round(x0, x1, 13); tf_round(x0, x1, 15); tf_round(x0, x1, 26); tf_round(x0, x1, 6);
  x0 += k2; x1 += k0 + 5u;
  o0 = x0; o1 = x1;
}

__device__ __forceinline__ float tf_uniform(unsigned bits) {
  return __uint_as_float((bits >> 9) | 0x3F800000u) - 1.0f;
}

__global__ __launch_bounds__(256) void gen_T(float *__restrict__ Tbuf) {
  int i = blockIdx.x * blockDim.x + threadIdx.x;  // 0..12287
  if (i >= NB * TE) return;
  unsigned o0, o1;
  threefry2x32(0u, (unsigned)i, o0, o1);
  Tbuf[i] = tf_uniform(o0 ^ o1) + 0.5f;  // T = u*(1.5-0.5)+0.5
}

// ---------------------------------------------------------------- f32 -> bf16 (8 elems/thread)
__global__ __launch_bounds__(256) void conv_bf16(const float *__restrict__ src,
                                                 ushort *__restrict__ dst) {
  const size_t i = ((size_t)blockIdx.x * 256 + threadIdx.x) * 8;
  float4 a = *(const float4 *)(src + i);
  float4 b = *(const float4 *)(src + i + 4);
  uint4 o;
  o.x = (unsigned)f2bf(a.x) | ((unsigned)f2bf(a.y) << 16);
  o.y = (unsigned)f2bf(a.z) | ((unsigned)f2bf(a.w) << 16);
  o.z = (unsigned)f2bf(b.x) | ((unsigned)f2bf(b.y) << 16);
  o.w = (unsigned)f2bf(b.z) | ((unsigned)f2bf(b.w) << 16);
  *(uint4 *)(dst + i) = o;
}

// ---------------------------------------------------------------- enc -> ench + encT
__global__ __launch_bounds__(256) void conv_encT(const float *__restrict__ enc,
                                                 ushort *__restrict__ ench,
                                                 ushort *__restrict__ encT) {
  const int n = blockIdx.z;
  const int d0 = blockIdx.x * 32;
  const int k0 = blockIdx.y * 32;
  __shared__ ushort t[32][33];
  const int row = threadIdx.x >> 3;      // k within tile
  const int c4 = (threadIdx.x & 7) * 4;  // d within tile
  float4 v = *(const float4 *)(enc + ((size_t)n * TE + k0 + row) * DM + d0 + c4);
  ushort4 e;
  e.x = f2bf(v.x); e.y = f2bf(v.y); e.z = f2bf(v.z); e.w = f2bf(v.w);
  t[row][c4 + 0] = e.x; t[row][c4 + 1] = e.y;
  t[row][c4 + 2] = e.z; t[row][c4 + 3] = e.w;
  *(ushort4 *)(ench + ((size_t)n * TE + k0 + row) * DM + d0 + c4) = e;
  __syncthreads();
  const int dr = threadIdx.x >> 3;       // d within tile
  const int kc = (threadIdx.x & 7) * 4;  // k within tile
  ushort4 o;
  o.x = t[kc + 0][dr]; o.y = t[kc + 1][dr];
  o.z = t[kc + 2][dr]; o.w = t[kc + 3][dr];
  *(ushort4 *)(encT + ((size_t)n * DM + d0 + dr) * TE + k0 + kc) = o;
}

// ---------------------------------------------------------------- bf16 MFMA GEMM
// C[m][n] = scale * sum_k A[m][k]*B[n][k]   (both operands K-contiguous)
// 128x128 tile, 4 waves (2x2), each wave 4x4 16x16x32 MFMA tiles, BK=32.
// Staging via global_load_lds width=16: wave w loads rows 32w..32w+31 of
// As and Bs (2 instrs each, 16 rows/instr; lane l -> row r0+(l>>2),
// ushort chunk (l&3)*8; LDS base wave-uniform).
__global__ __launch_bounds__(256) void gemm_bf16_mfma(
    const ushort *__restrict__ Ag, const ushort *__restrict__ Bg,
    float *__restrict__ Cg, int K, int N, size_t sA, size_t sB, size_t sC,
    float scale) {
  const int nb = blockIdx.z;
  const int n0 = blockIdx.x * 128;
  const int m0 = blockIdx.y * 128;
  const int tid = threadIdx.x;
  const int wave = tid >> 6, lane = tid & 63;
  const int wm = (wave >> 1) * 64, wn = (wave & 1) * 64;
  const int fr = lane & 15, quad = lane >> 4;
  const ushort *A = Ag + nb * sA + (size_t)m0 * K;
  const ushort *B = Bg + nb * sB + (size_t)n0 * K;
  __shared__ __align__(16) ushort As[128 * 32];
  __shared__ __align__(16) ushort Bs[128 * 32];
  f32x4 acc[4][4];
#pragma unroll
  for (int i = 0; i < 4; ++i)
#pragma unroll
    for (int c = 0; c < 4; ++c) acc[i][c] = (f32x4){0.f, 0.f, 0.f, 0.f};

  const int r0 = 32 * wave + (lane >> 2);  // global row this lane feeds
  const int c0 = (lane & 3) * 8;           // ushort chunk within the row
  const ushort *gA0 = A + (size_t)r0 * K + c0;
  const ushort *gA1 = A + (size_t)(r0 + 16) * K + c0;
  const ushort *gB0 = B + (size_t)r0 * K + c0;
  const ushort *gB1 = B + (size_t)(r0 + 16) * K + c0;
  ushort *lA0 = &As[(32 * wave) * 32];
  ushort *lA1 = &As[(32 * wave + 16) * 32];
  ushort *lB0 = &Bs[(32 * wave) * 32];
  ushort *lB1 = &Bs[(32 * wave + 16) * 32];

  for (int kb = 0; kb < K; kb += 32) {
    __syncthreads();  // prior compute finished reading LDS
    GLDS16(gA0 + kb, lA0);
    GLDS16(gA1 + kb, lA1);
    GLDS16(gB0 + kb, lB0);
    GLDS16(gB1 + kb, lB1);
    __syncthreads();  // compiler drains vmcnt before barrier -> data ready
    bf16x8 af[4], bfv[4];
#pragma unroll
    for (int i = 0; i < 4; ++i)
      af[i] = *(const bf16x8 *)(&As[(wm + i * 16 + fr) * 32 + quad * 8]);
#pragma unroll
    for (int c = 0; c < 4; ++c)
      bfv[c] = *(const bf16x8 *)(&Bs[(wn + c * 16 + fr) * 32 + quad * 8]);
#pragma unroll
    for (int i = 0; i < 4; ++i)
#pragma unroll
      for (int c = 0; c < 4; ++c)
        acc[i][c] = __builtin_amdgcn_mfma_f32_16x16x32_bf16(af[i], bfv[c],
                                                            acc[i][c], 0, 0, 0);
  }
  float *Cb = Cg + nb * sC;
#pragma unroll
  for (int i = 0; i < 4; ++i)
#pragma unroll
    for (int c = 0; c < 4; ++c)
#pragma unroll
      for (int r = 0; r < 4; ++r)
        Cb[(size_t)(m0 + wm + i * 16 + quad * 4 + r) * N + n0 + wn + c * 16 + fr] =
            acc[i][c][r] * scale;
}

// ---------------------------------------------------------------- softmax
__global__ __launch_bounds__(64) void softmax_rows(
    const float *__restrict__ scores, float *__restrict__ out1) {
  const int row = blockIdx.x;  // n*TD + j
  const int n = row >> 10;
  const int j = row & 1023;
  const int tid = threadIdx.x;
  const float2 *s2 = (const float2 *)(scores + (size_t)row * TE);
  float2 a0 = s2[tid], a1 = s2[tid + 64], a2 = s2[tid + 128];
  float m = fmaxf(fmaxf(fmaxf(a0.x, a0.y), fmaxf(a1.x, a1.y)),
                  fmaxf(a2.x, a2.y));
#pragma unroll
  for (int off = 32; off; off >>= 1) m = fmaxf(m, __shfl_xor(m, off));
  float e0 = __expf(a0.x - m), e1 = __expf(a0.y - m);
  float e2 = __expf(a1.x - m), e3 = __expf(a1.y - m);
  float e4 = __expf(a2.x - m), e5 = __expf(a2.y - m);
  float sum = ((e0 + e1) + (e2 + e3)) + (e4 + e5);
#pragma unroll
  for (int off = 32; off; off >>= 1) sum += __shfl_xor(sum, off);
  const float r = 1.0f / sum;
  float2 *d2 = (float2 *)(out1 + (size_t)n * (2 * TD * TE) + (size_t)j * TE);
  d2[tid] = make_float2(e0 * r, e1 * r);
  d2[tid + 64] = make_float2(e2 * r, e3 * r);
  d2[tid + 128] = make_float2(e4 * r, e5 * r);
}

// ---------------------------------------------------------------- cond_prob (parallel)
__global__ __launch_bounds__(256) void cond_prob2(
    const float *__restrict__ scores, const float *__restrict__ Tbuf,
    float *__restrict__ cpT) {
  const int n = blockIdx.z;
  const int j0 = blockIdx.y * 64;
  const int k0 = blockIdx.x * 64;
  const int tid = threadIdx.x;
  __shared__ float eL[82][65];

  {
    const int c4 = (tid & 15) * 4;
    const int r0 = tid >> 4;  // 0..15
    float4 tv = *(const float4 *)(Tbuf + n * TE + k0 + c4);
    const float it0 = 1.0f / tv.x, it1 = 1.0f / tv.y, it2 = 1.0f / tv.z,
                it3 = 1.0f / tv.w;
#pragma unroll
    for (int p = 0; p < 6; ++p) {
      const int r = r0 + p * 16;
      if (r < 82) {
        const int j = j0 + r;
        float4 s;
        if (j < TD) {
          s = *(const float4 *)(scores + ((size_t)n * TD + j) * TE + k0 + c4);
          s.x = __expf(s.x * it0); s.y = __expf(s.y * it1);
          s.z = __expf(s.z * it2); s.w = __expf(s.w * it3);
        } else {
          s = make_float4(0.f, 0.f, 0.f, 0.f);
        }
        eL[r][c4 + 0] = s.x; eL[r][c4 + 1] = s.y;
        eL[r][c4 + 2] = s.z; eL[r][c4 + 3] = s.w;
      }
    }
  }
  __syncthreads();

  const int k = tid & 63;
  const int jl0 = (tid >> 6) * 16;
  float e_r[35];
#pragma unroll
  for (int t = 0; t < 35; ++t) e_r[t] = eL[jl0 + t][k];
  float win = 0.f;
#pragma unroll
  for (int t = 15; t <= 33; ++t) win += e_r[t];
  float cp[16];
#pragma unroll
  for (int jl = 15; jl >= 0; --jl) {
    cp[jl] = e_r[jl] / (win + 1e-8f);
    if (jl > 0) win += e_r[jl - 1] - e_r[jl + 18];
  }
  float *dst = cpT + ((size_t)n * TE + k0 + k) * TD + j0 + jl0;
#pragma unroll
  for (int q = 0; q < 4; ++q)
    *(float4 *)(dst + q * 4) =
        make_float4(cp[q * 4], cp[q * 4 + 1], cp[q * 4 + 2], cp[q * 4 + 3]);
}

// ---------------------------------------------------------------- phase 1 (a scan)
// Round-6 version (best measured). Single wave per batch n. 16 j per lane.
// Wave-synchronous LDS exchange of q = a*cp (20-float backward halo).
// No __syncthreads, no HW lgkmcnt(0): same-wave DS ops execute in program
// order; zero-instruction compiler fences order writes<->reads. cp prefetch
// depth 3 (unroll-4, named float4 register sets).
// LDS layout: logical J = j+24 in [0,1048) mapped to phys = J + (J>>4)*4.
#define P1PH(J) ((J) + (((J) >> 4) << 2))

#define P1_BODY(CU0, CU1, CU2, CU3, CL0, CL1, CL2, CL3, kk)                   \
  {                                                                           \
    /* prefetch cp column used at step (kk)+3 (column shift: col(k)=k-1) */   \
    const int pc = ((kk) + 2 < TE) ? ((kk) + 2) : (TE - 1);                   \
    const float *pp = cpn + (size_t)pc * TD + j0;                             \
    CL0 = *(const float4 *)(pp);                                              \
    CL1 = *(const float4 *)(pp + 4);                                          \
    CL2 = *(const float4 *)(pp + 8);                                          \
    CL3 = *(const float4 *)(pp + 12);                                         \
    float4 q0 = make_float4(a[0] * CU0.x, a[1] * CU0.y,                       \
                            a[2] * CU0.z, a[3] * CU0.w);                      \
    float4 q1 = make_float4(a[4] * CU1.x, a[5] * CU1.y,                       \
                            a[6] * CU1.z, a[7] * CU1.w);                      \
    float4 q2 = make_float4(a[8] * CU2.x, a[9] * CU2.y,                       \
                            a[10] * CU2.z, a[11] * CU2.w);                    \
    float4 q3 = make_float4(a[12] * CU3.x, a[13] * CU3.y,                     \
                            a[14] * CU3.z, a[15] * CU3.w);                    \
    *(float4 *)(w01p) = q0;                                                   \
    *(float4 *)(w01p + 4) = q1;                                               \
    *(float4 *)(w23p) = q2;                                                   \
    *(float4 *)(w23p + 4) = q3;                                               \
    asm volatile("" ::: "memory"); /* order writes before reads (compiler) */ \
    float4 h1 = *(const float4 *)(rdA);                                       \
    float4 h2 = *(const float4 *)(rdA + 4);                                   \
    float4 h3 = *(const float4 *)(rdA + 8);                                   \
    float4 h4 = *(const float4 *)(rdB);                                       \
    float4 h5 = *(const float4 *)(rdB + 4);                                   \
    asm volatile("" ::: "memory"); /* order reads before next-step writes */  \
    float w[38];                                                              \
    w[4] = h1.x;  w[5] = h1.y;  w[6] = h1.z;  w[7] = h1.w;                    \
    w[8] = h2.x;  w[9] = h2.y;  w[10] = h2.z; w[11] = h2.w;                   \
    w[12] = h3.x; w[13] = h3.y; w[14] = h3.z; w[15] = h3.w;                   \
    w[16] = h4.x; w[17] = h4.y; w[18] = h4.z; w[19] = h4.w;                   \
    w[20] = h5.x; w[21] = h5.y; w[22] = h5.z; w[23] = h5.w;                   \
    w[24] = q0.x; w[25] = q0.y; w[26] = q0.z; w[27] = q0.w;                   \
    w[28] = q1.x; w[29] = q1.y; w[30] = q1.z; w[31] = q1.w;                   \
    w[32] = q2.x; w[33] = q2.y; w[34] = q2.z; w[35] = q2.w;                   \
    w[36] = q3.x; w[37] = q3.y;                                               \
    /* window for j=j0+i is sum w[i+4 .. i+22]; two balanced trees + slides */\
    float t0 = w[4] + w[5], t1 = w[6] + w[7], t2 = w[8] + w[9];               \
    float t3 = w[10] + w[11], t4 = w[12] + w[13], t5 = w[14] + w[15];         \
    float t6 = w[16] + w[17], t7 = w[18] + w[19], t8 = w[20] + w[21];         \
    float s0 = (((t0 + t1) + (t2 + t3)) + ((t4 + t5) + (t6 + t7))) +          \
               (t8 + w[22]);                                                  \
    a[0] = s0;                                                                \
    s0 += w[23] - w[4];  a[1] = s0;                                           \
    s0 += w[24] - w[5];  a[2] = s0;                                           \
    s0 += w[25] - w[6];  a[3] = s0;                                           \
    s0 += w[26] - w[7];  a[4] = s0;                                           \
    s0 += w[27] - w[8];  a[5] = s0;                                           \
    s0 += w[28] - w[9];  a[6] = s0;                                           \
    s0 += w[29] - w[10]; a[7] = s0;                                           \
    float u4 = w[20] + w[21], u5 = w[22] + w[23], u6 = w[24] + w[25];         \
    float u7 = w[26] + w[27], u8 = w[28] + w[29];                             \
    float s1 = (((t4 + t5) + (t6 + t7)) + ((u4 + u5) + (u6 + u7))) +          \
               (u8 + w[30]);                                                  \
    a[8] = s1;                                                                \
    s1 += w[31] - w[12]; a[9] = s1;                                           \
    s1 += w[32] - w[13]; a[10] = s1;                                          \
    s1 += w[33] - w[14]; a[11] = s1;                                          \
    s1 += w[34] - w[15]; a[12] = s1;                                          \
    s1 += w[35] - w[16]; a[13] = s1;                                          \
    s1 += w[36] - w[17]; a[14] = s1;                                          \
    s1 += w[37] - w[18]; a[15] = s1;                                          \
    float *ao = an + (size_t)(kk)*TD + j0;                                    \
    *(float4 *)(ao) = make_float4(a[0], a[1], a[2], a[3]);                    \
    *(float4 *)(ao + 4) = make_float4(a[4], a[5], a[6], a[7]);                \
    *(float4 *)(ao + 8) = make_float4(a[8], a[9], a[10], a[11]);              \
    *(float4 *)(ao + 12) = make_float4(a[12], a[13], a[14], a[15]);           \
  }

__global__ __launch_bounds__(64) void phase1_a(
    const float *__restrict__ cpT, float *__restrict__ aT) {
  const int n = blockIdx.x;
  const int L = threadIdx.x;  // 0..63, one wave
  const int j0 = L * 16;
  __shared__ __align__(16) float qbuf[1320];  // 66 groups * 20 floats

  // zero the 24-float logical pad (j in [-24,-1] -> J in [0,24))
  if (L < 24) qbuf[P1PH(L)] = 0.f;

  const float *cpn = cpT + (size_t)n * TE * TD;
  float *an = aT + (size_t)n * TE * TD;

  // lane-local LDS pointers (all b128-aligned, conflict-free under swizzle)
  float *w01p = &qbuf[P1PH(j0 + 24)];
  float *w23p = &qbuf[P1PH(j0 + 32)];
  const float *rdA = &qbuf[P1PH(j0) + 4];
  const float *rdB = &qbuf[P1PH(j0 + 16)];

  float a[16];
#pragma unroll
  for (int i = 0; i < 16; ++i) a[i] = 0.f;
  if (L == 0) a[0] = 1.f;

  // prologue: steps 0,1 use cp column 0; step 2 uses column 1
  float4 cpA0, cpA1, cpA2, cpA3, cpB0, cpB1, cpB2, cpB3;
  float4 cpC0, cpC1, cpC2, cpC3, cpD0, cpD1, cpD2, cpD3;
  {
    const float *p0 = cpn + j0;
    cpA0 = *(const float4 *)(p0);
    cpA1 = *(const float4 *)(p0 + 4);
    cpA2 = *(const float4 *)(p0 + 8);
    cpA3 = *(const float4 *)(p0 + 12);
    cpB0 = cpA0; cpB1 = cpA1; cpB2 = cpA2; cpB3 = cpA3;
    const float *p1 = cpn + (size_t)TD + j0;
    cpC0 = *(const float4 *)(p1);
    cpC1 = *(const float4 *)(p1 + 4);
    cpC2 = *(const float4 *)(p1 + 8);
    cpC3 = *(const float4 *)(p1 + 12);
  }

  for (int k = 0; k < TE; k += 4) {  // TE = 384 = 4*96
    P1_BODY(cpA0, cpA1, cpA2, cpA3, cpD0, cpD1, cpD2, cpD3, k);
    P1_BODY(cpB0, cpB1, cpB2, cpB3, cpA0, cpA1, cpA2, cpA3, k + 1);
    P1_BODY(cpC0, cpC1, cpC2, cpC3, cpB0, cpB1, cpB2, cpB3, k + 2);
    P1_BODY(cpD0, cpD1, cpD2, cpD3, cpC0, cpC1, cpC2, cpC3, k + 3);
  }
}

// ---------------------------------------------------------------- phase 2 (B)
__global__ __launch_bounds__(256) void phase2_B(
    const float *__restrict__ cpT, const float *__restrict__ aT,
    float *__restrict__ BT) {
  const int k = blockIdx.x;
  const int n = blockIdx.y;
  const int tid = threadIdx.x;
  const float *cpc = cpT + ((size_t)n * TE + k) * TD;
  const float *ac = aT + ((size_t)n * TE + k) * TD;
  __shared__ float a_l[20 + TD];
  __shared__ float cp_l[TD + 24];
  float4 av = *(const float4 *)(ac + tid * 4);
  *(float4 *)(&a_l[20 + tid * 4]) = av;
  float4 cv = *(const float4 *)(cpc + tid * 4);
  if (tid == 255) cv.w = 0.f;  // cp[1023] never contributes (clamp rule)
  *(float4 *)(&cp_l[tid * 4]) = cv;
  if (tid < 20) a_l[tid] = 0.f;
  if (tid < 24) cp_l[TD + tid] = 0.f;
  __syncthreads();
  const int j0 = tid * 4;
  float ar[21], cpr[21];
#pragma unroll
  for (int t = 0; t < 21; ++t) ar[t] = a_l[20 + j0 - 19 + t];
#pragma unroll
  for (int t = 0; t < 21; ++t) cpr[t] = cp_l[j0 + t];
  float Bo[4];
#pragma unroll
  for (int i = 0; i < 4; ++i) {
    float W = 0.f, acc2 = 0.f;
#pragma unroll
    for (int d = 19; d >= 2; --d) {
      W += cpr[i + 19 - d];
      acc2 = fmaf(ar[19 + i - d], W, acc2);
    }
    Bo[i] = acc2;
  }
  *(float4 *)(BT + ((size_t)n * TE + k) * TD + j0) =
      make_float4(Bo[0], Bo[1], Bo[2], Bo[3]);
}

// ---------------------------------------------------------------- transpose (+ bf16 copy)
__global__ __launch_bounds__(256) void transpose_B(
    const float *__restrict__ BT, float *__restrict__ out1,
    ushort *__restrict__ Bh) {
  __shared__ float tile[32][33];
  const int n = blockIdx.z;
  const int k0 = blockIdx.x * 32;
  const int j0 = blockIdx.y * 32;
  const int tx = threadIdx.x & 31;
  const int ty = threadIdx.x >> 5;  // 0..7
  const float *src = BT + (size_t)n * TE * TD;
#pragma unroll
  for (int r = 0; r < 4; ++r) {
    const int kk = ty + r * 8;
    tile[kk][tx] = src[(size_t)(k0 + kk) * TD + j0 + tx];
  }
  __syncthreads();
  float *dst = out1 + (size_t)n * (2 * TD * TE) + (size_t)TD * TE;
#pragma unroll
  for (int r = 0; r < 4; ++r) {
    const int jj = ty + r * 8;
    const float val = tile[tx][jj];
    dst[(size_t)(j0 + jj) * TE + k0 + tx] = val;
    Bh[((size_t)n * TD + j0 + jj) * TE + k0 + tx] = f2bf(val);
  }
}

// ---------------------------------------------------------------- launch
extern "C" void kernel_launch(void *const *d_in, const int *in_sizes, int n_in,
                              void *d_out, int out_size, void *d_ws,
                              size_t ws_size, hipStream_t stream) {
  (void)in_sizes; (void)n_in; (void)out_size; (void)ws_size;
  const float *enc = (const float *)d_in[0];  // [32][384][512]
  const float *mel = (const float *)d_in[1];  // [32][1024][512]
  float *out = (float *)d_out;
  float *out0 = out;                         // att_out [32][1024][512]
  float *out1 = out + (size_t)NB * TD * DM;  // stacked [32][2][1024][384]

  const size_t SZ = (size_t)NB * TD * TE;    // 12,582,912 floats
  float *ws = (float *)d_ws;
  float *ws_scores = ws;       // scores [n][j][k]; later BT
  float *ws_cpT = ws + SZ;     // cond_prob [n][k][j] (holds ench+melh before)
  float *ws_aT = ws + 2 * SZ;  // a [n][k][j] (holds Bh after phase2)
  float *ws_T = ws + 3 * SZ;   // T [n][k]
  ushort *encTb = (ushort *)(ws + 3 * SZ + NB * TE);  // encT bf16 [n][d][k]
  ushort *ench = (ushort *)ws_cpT;                    // bf16 [n][k][d]
  ushort *melh = (ushort *)ws_cpT + (size_t)NB * TE * DM;  // bf16 [n][j][d]
  ushort *Bh = (ushort *)ws_aT;                       // bf16 [n][j][k]
  float *ws_BT = ws_scores;

  conv_bf16<<<(NB * TD * DM) / (256 * 8), 256, 0, stream>>>(mel, melh);
  conv_encT<<<dim3(DM / 32, TE / 32, NB), 256, 0, stream>>>(enc, ench, encTb);
  gen_T<<<48, 256, 0, stream>>>(ws_T);
  gemm_bf16_mfma<<<dim3(TE / 128, TD / 128, NB), 256, 0, stream>>>(
      melh, ench, ws_scores, DM, TE, (size_t)TD * DM, (size_t)TE * DM,
      (size_t)TD * TE, 0.0441941738241592f);
  softmax_rows<<<NB * TD, 64, 0, stream>>>(ws_scores, out1);
  cond_prob2<<<dim3(TE / 64, TD / 64, NB), 256, 0, stream>>>(ws_scores, ws_T, ws_cpT);
  phase1_a<<<NB, 64, 0, stream>>>(ws_cpT, ws_aT);
  phase2_B<<<dim3(TE, NB), 256, 0, stream>>>(ws_cpT, ws_aT, ws_BT);
  transpose_B<<<dim3(TE / 32, TD / 32, NB), 256, 0, stream>>>(ws_BT, out1, Bh);
  gemm_bf16_mfma<<<dim3(DM / 128, TD / 128, NB), 256, 0, stream>>>(
      Bh, encTb, out0, TE, DM, (size_t)TD * TE, (size_t)DM * TE,
      (size_t)TD * DM, 1.0f);
}

// Round 6
// 498.132 us; speedup vs baseline: 1.1044x; 1.0390x over previous
//
#include <hip/hip_runtime.h>
#include <hip/hip_bf16.h>

// MoBoAlignerAttention on MI355X — round 9.
// Changes vs round 8:
//  * softmax_rows FUSED into the phase1 dispatch (phase1_softmax): blocks
//    0..31 run the serial scan (1 wave each, ~32 CUs), blocks 32..32799 run
//    softmax rows on the other ~224 CUs CONCURRENTLY. Removes softmax's
//    serial ~25 µs (stream is serial; separate launches can't overlap).
//  * gen_T folded into cond_prob2 (threefry into a 64-float LDS table per
//    block; 16x redundant compute, trivial) — one fewer dispatch + no Tbuf
//    round-trip.
//  * phase1 cp prefetch depth 3 -> 5 (unroll-6, six named float4 sets):
//    more slack between a-store issue and cp-use vmcnt wait (in-order
//    counter couples them). Arithmetic bit-identical.
//  * GEMM (global_load_lds width=16) and everything else as round 8.
//
// Pipeline:
//  conv_bf16     : mel f32 -> melh bf16 [n][j][d]
//  conv_encT     : enc f32 -> ench bf16 [n][k][d]  +  encT bf16 [n][d][k]
//  gemm_mfma     : scores = melh @ ench^T / sqrt(512)        (bf16 MFMA)
//  cond_prob2    : T inline (threefry); cp = e/(window_19(e)+1e-8) -> cpT
//  phase1_softmax: scan a_k (32 blocks) || softmax -> out1 (32768 blocks)
//  phase2_B      : B[j,k] = sum_{d=2..19} a[j-d,k]*W_{20-d}(j,k)
//  transpose_B   : BT -> d_out B slot (f32) + Bh bf16 [n][j][k]
//  gemm_mfma     : att = Bh @ encT^T                         (bf16 MFMA)

#define NB 32
#define TD 1024
#define TE 384
#define DM 512

typedef __attribute__((ext_vector_type(8))) short bf16x8;
typedef __attribute__((ext_vector_type(4))) float f32x4;

#define GLDS16(g, l)                                                          \
  __builtin_amdgcn_global_load_lds(                                           \
      (const __attribute__((address_space(1))) unsigned int *)(g),            \
      (__attribute__((address_space(3))) unsigned int *)(l), 16, 0, 0)

// f32 -> bf16 round-to-nearest-even
__device__ __forceinline__ ushort f2bf(float f) {
  unsigned u = __float_as_uint(f);
  return (ushort)((u + 0x7FFFu + ((u >> 16) & 1u)) >> 16);
}

// ---------------------------------------------------------------- threefry
__device__ __forceinline__ void tf_round(unsigned &x0, unsigned &x1, int r) {
  x0 += x1;
  x1 = (x1 << r) | (x1 >> (32 - r));
  x1 ^= x0;
}

__device__ __forceinline__ void threefry2x32(unsigned c0, unsigned c1,
                                             unsigned &o0, unsigned &o1) {
  const unsigned k0 = 0u, k1 = 1234u;
  const unsigned k2 = 0u ^ 1234u ^ 0x1BD11BDAu;
  unsigned x0 = c0 + k0, x1 = c1 + k1;
  tf_round(x0, x1, 13); tf_round(x0, x1, 15); tf_round(x0, x1, 26); tf_round(x0, x1, 6);
  x0 += k1; x1 += k2 + 1u;
  tf_round(x0, x1, 17); tf_round(x0, x1, 29); tf_round(x0, x1, 16); tf_round(x0, x1, 24);
  x0 += k2; x1 += k0 + 2u;
  tf_round(x0, x1, 13); tf_round(x0, x1, 15); tf_round(x0, x1, 26); tf_round(x0, x1, 6);
  x0 += k0; x1 += k1 + 3u;
  tf_round(x0, x1, 17); tf_round(x0, x1, 29); tf_round(x0, x1, 16); tf_round(x0, x1, 24);
  x0 += k1; x1 += k2 + 4u;
  tf_round(x0, x1, 13); tf_round(x0, x1, 15); tf_round(x0, x1, 26); tf_round(x0, x1, 6);
  x0 += k2; x1 += k0 + 5u;
  o0 = x0; o1 = x1;
}

__device__ __forceinline__ float tf_uniform(unsigned bits) {
  return __uint_as_float((bits >> 9) | 0x3F800000u) - 1.0f;
}

// ---------------------------------------------------------------- f32 -> bf16 (8 elems/thread)
__global__ __launch_bounds__(256) void conv_bf16(const float *__restrict__ src,
                                                 ushort *__restrict__ dst) {
  const size_t i = ((size_t)blockIdx.x * 256 + threadIdx.x) * 8;
  float4 a = *(const float4 *)(src + i);
  float4 b = *(const float4 *)(src + i + 4);
  uint4 o;
  o.x = (unsigned)f2bf(a.x) | ((unsigned)f2bf(a.y) << 16);
  o.y = (unsigned)f2bf(a.z) | ((unsigned)f2bf(a.w) << 16);
  o.z = (unsigned)f2bf(b.x) | ((unsigned)f2bf(b.y) << 16);
  o.w = (unsigned)f2bf(b.z) | ((unsigned)f2bf(b.w) << 16);
  *(uint4 *)(dst + i) = o;
}

// ---------------------------------------------------------------- enc -> ench + encT
__global__ __launch_bounds__(256) void conv_encT(const float *__restrict__ enc,
                                                 ushort *__restrict__ ench,
                                                 ushort *__restrict__ encT) {
  const int n = blockIdx.z;
  const int d0 = blockIdx.x * 32;
  const int k0 = blockIdx.y * 32;
  __shared__ ushort t[32][33];
  const int row = threadIdx.x >> 3;      // k within tile
  const int c4 = (threadIdx.x & 7) * 4;  // d within tile
  float4 v = *(const float4 *)(enc + ((size_t)n * TE + k0 + row) * DM + d0 + c4);
  ushort4 e;
  e.x = f2bf(v.x); e.y = f2bf(v.y); e.z = f2bf(v.z); e.w = f2bf(v.w);
  t[row][c4 + 0] = e.x; t[row][c4 + 1] = e.y;
  t[row][c4 + 2] = e.z; t[row][c4 + 3] = e.w;
  *(ushort4 *)(ench + ((size_t)n * TE + k0 + row) * DM + d0 + c4) = e;
  __syncthreads();
  const int dr = threadIdx.x >> 3;       // d within tile
  const int kc = (threadIdx.x & 7) * 4;  // k within tile
  ushort4 o;
  o.x = t[kc + 0][dr]; o.y = t[kc + 1][dr];
  o.z = t[kc + 2][dr]; o.w = t[kc + 3][dr];
  *(ushort4 *)(encT + ((size_t)n * DM + d0 + dr) * TE + k0 + kc) = o;
}

// ---------------------------------------------------------------- bf16 MFMA GEMM
// C[m][n] = scale * sum_k A[m][k]*B[n][k]   (both operands K-contiguous)
// 128x128 tile, 4 waves (2x2), each wave 4x4 16x16x32 MFMA tiles, BK=32.
// Staging via global_load_lds width=16 (m97 pattern).
__global__ __launch_bounds__(256) void gemm_bf16_mfma(
    const ushort *__restrict__ Ag, const ushort *__restrict__ Bg,
    float *__restrict__ Cg, int K, int N, size_t sA, size_t sB, size_t sC,
    float scale) {
  const int nb = blockIdx.z;
  const int n0 = blockIdx.x * 128;
  const int m0 = blockIdx.y * 128;
  const int tid = threadIdx.x;
  const int wave = tid >> 6, lane = tid & 63;
  const int wm = (wave >> 1) * 64, wn = (wave & 1) * 64;
  const int fr = lane & 15, quad = lane >> 4;
  const ushort *A = Ag + nb * sA + (size_t)m0 * K;
  const ushort *B = Bg + nb * sB + (size_t)n0 * K;
  __shared__ __align__(16) ushort As[128 * 32];
  __shared__ __align__(16) ushort Bs[128 * 32];
  f32x4 acc[4][4];
#pragma unroll
  for (int i = 0; i < 4; ++i)
#pragma unroll
    for (int c = 0; c < 4; ++c) acc[i][c] = (f32x4){0.f, 0.f, 0.f, 0.f};

  const int r0 = 32 * wave + (lane >> 2);  // global row this lane feeds
  const int c0 = (lane & 3) * 8;           // ushort chunk within the row
  const ushort *gA0 = A + (size_t)r0 * K + c0;
  const ushort *gA1 = A + (size_t)(r0 + 16) * K + c0;
  const ushort *gB0 = B + (size_t)r0 * K + c0;
  const ushort *gB1 = B + (size_t)(r0 + 16) * K + c0;
  ushort *lA0 = &As[(32 * wave) * 32];
  ushort *lA1 = &As[(32 * wave + 16) * 32];
  ushort *lB0 = &Bs[(32 * wave) * 32];
  ushort *lB1 = &Bs[(32 * wave + 16) * 32];

  for (int kb = 0; kb < K; kb += 32) {
    __syncthreads();  // prior compute finished reading LDS
    GLDS16(gA0 + kb, lA0);
    GLDS16(gA1 + kb, lA1);
    GLDS16(gB0 + kb, lB0);
    GLDS16(gB1 + kb, lB1);
    __syncthreads();  // compiler drains vmcnt before barrier -> data ready
    bf16x8 af[4], bfv[4];
#pragma unroll
    for (int i = 0; i < 4; ++i)
      af[i] = *(const bf16x8 *)(&As[(wm + i * 16 + fr) * 32 + quad * 8]);
#pragma unroll
    for (int c = 0; c < 4; ++c)
      bfv[c] = *(const bf16x8 *)(&Bs[(wn + c * 16 + fr) * 32 + quad * 8]);
#pragma unroll
    for (int i = 0; i < 4; ++i)
#pragma unroll
      for (int c = 0; c < 4; ++c)
        acc[i][c] = __builtin_amdgcn_mfma_f32_16x16x32_bf16(af[i], bfv[c],
                                                            acc[i][c], 0, 0, 0);
  }
  float *Cb = Cg + nb * sC;
#pragma unroll
  for (int i = 0; i < 4; ++i)
#pragma unroll
    for (int c = 0; c < 4; ++c)
#pragma unroll
      for (int r = 0; r < 4; ++r)
        Cb[(size_t)(m0 + wm + i * 16 + quad * 4 + r) * N + n0 + wn + c * 16 + fr] =
            acc[i][c][r] * scale;
}

// ---------------------------------------------------------------- cond_prob (parallel, T inline)
__global__ __launch_bounds__(256) void cond_prob2(
    const float *__restrict__ scores, float *__restrict__ cpT) {
  const int n = blockIdx.z;
  const int j0 = blockIdx.y * 64;
  const int k0 = blockIdx.x * 64;
  const int tid = threadIdx.x;
  __shared__ float eL[82][65];
  __shared__ float Tl[64];

  if (tid < 64) {
    unsigned o0, o1;
    threefry2x32(0u, (unsigned)(n * TE + k0 + tid), o0, o1);
    Tl[tid] = tf_uniform(o0 ^ o1) + 0.5f;  // T = u*(1.5-0.5)+0.5
  }
  __syncthreads();

  {
    const int c4 = (tid & 15) * 4;
    const int r0 = tid >> 4;  // 0..15
    const float it0 = 1.0f / Tl[c4 + 0], it1 = 1.0f / Tl[c4 + 1],
                it2 = 1.0f / Tl[c4 + 2], it3 = 1.0f / Tl[c4 + 3];
#pragma unroll
    for (int p = 0; p < 6; ++p) {
      const int r = r0 + p * 16;
      if (r < 82) {
        const int j = j0 + r;
        float4 s;
        if (j < TD) {
          s = *(const float4 *)(scores + ((size_t)n * TD + j) * TE + k0 + c4);
          s.x = __expf(s.x * it0); s.y = __expf(s.y * it1);
          s.z = __expf(s.z * it2); s.w = __expf(s.w * it3);
        } else {
          s = make_float4(0.f, 0.f, 0.f, 0.f);
        }
        eL[r][c4 + 0] = s.x; eL[r][c4 + 1] = s.y;
        eL[r][c4 + 2] = s.z; eL[r][c4 + 3] = s.w;
      }
    }
  }
  __syncthreads();

  const int k = tid & 63;
  const int jl0 = (tid >> 6) * 16;
  float e_r[35];
#pragma unroll
  for (int t = 0; t < 35; ++t) e_r[t] = eL[jl0 + t][k];
  float win = 0.f;
#pragma unroll
  for (int t = 15; t <= 33; ++t) win += e_r[t];
  float cp[16];
#pragma unroll
  for (int jl = 15; jl >= 0; --jl) {
    cp[jl] = e_r[jl] / (win + 1e-8f);
    if (jl > 0) win += e_r[jl - 1] - e_r[jl + 18];
  }
  float *dst = cpT + ((size_t)n * TE + k0 + k) * TD + j0 + jl0;
#pragma unroll
  for (int q = 0; q < 4; ++q)
    *(float4 *)(dst + q * 4) =
        make_float4(cp[q * 4], cp[q * 4 + 1], cp[q * 4 + 2], cp[q * 4 + 3]);
}

// ---------------------------------------------------------------- phase 1 scan + softmax (fused)
// Blocks 0..NB-1: round-6 wave-synchronous scan (prefetch depth 5, unroll 6).
// Blocks NB..NB+NB*TD-1: one softmax row each (64 threads, no LDS).
#define P1PH(J) ((J) + (((J) >> 4) << 2))

#define P1_BODY(CU0, CU1, CU2, CU3, CL0, CL1, CL2, CL3, kk)                   \
  {                                                                           \
    /* prefetch cp column used at step (kk)+5 (column shift: col(k)=k-1) */   \
    const int pc = ((kk) + 4 < TE) ? ((kk) + 4) : (TE - 1);                   \
    const float *pp = cpn + (size_t)pc * TD + j0;                             \
    CL0 = *(const float4 *)(pp);                                              \
    CL1 = *(const float4 *)(pp + 4);                                          \
    CL2 = *(const float4 *)(pp + 8);                                          \
    CL3 = *(const float4 *)(pp + 12);                                         \
    float4 q0 = make_float4(a[0] * CU0.x, a[1] * CU0.y,                       \
                            a[2] * CU0.z, a[3] * CU0.w);                      \
    float4 q1 = make_float4(a[4] * CU1.x, a[5] * CU1.y,                       \
                            a[6] * CU1.z, a[7] * CU1.w);                      \
    float4 q2 = make_float4(a[8] * CU2.x, a[9] * CU2.y,                       \
                            a[10] * CU2.z, a[11] * CU2.w);                    \
    float4 q3 = make_float4(a[12] * CU3.x, a[13] * CU3.y,                     \
                            a[14] * CU3.z, a[15] * CU3.w);                    \
    *(float4 *)(w01p) = q0;                                                   \
    *(float4 *)(w01p + 4) = q1;                                               \
    *(float4 *)(w23p) = q2;                                                   \
    *(float4 *)(w23p + 4) = q3;                                               \
    asm volatile("" ::: "memory"); /* order writes before reads (compiler) */ \
    float4 h1 = *(const float4 *)(rdA);                                       \
    float4 h2 = *(const float4 *)(rdA + 4);                                   \
    float4 h3 = *(const float4 *)(rdA + 8);                                   \
    float4 h4 = *(const float4 *)(rdB);                                       \
    float4 h5 = *(const float4 *)(rdB + 4);                                   \
    asm volatile("" ::: "memory"); /* order reads before next-step writes */  \
    float w[38];                                                              \
    w[4] = h1.x;  w[5] = h1.y;  w[6] = h1.z;  w[7] = h1.w;                    \
    w[8] = h2.x;  w[9] = h2.y;  w[10] = h2.z; w[11] = h2.w;                   \
    w[12] = h3.x; w[13] = h3.y; w[14] = h3.z; w[15] = h3.w;                   \
    w[16] = h4.x; w[17] = h4.y; w[18] = h4.z; w[19] = h4.w;                   \
    w[20] = h5.x; w[21] = h5.y; w[22] = h5.z; w[23] = h5.w;                   \
    w[24] = q0.x; w[25] = q0.y; w[26] = q0.z; w[27] = q0.w;                   \
    w[28] = q1.x; w[29] = q1.y; w[30] = q1.z; w[31] = q1.w;                   \
    w[32] = q2.x; w[33] = q2.y; w[34] = q2.z; w[35] = q2.w;                   \
    w[36] = q3.x; w[37] = q3.y;                                               \
    /* window for j=j0+i is sum w[i+4 .. i+22]; two balanced trees + slides */\
    float t0 = w[4] + w[5], t1 = w[6] + w[7], t2 = w[8] + w[9];               \
    float t3 = w[10] + w[11], t4 = w[12] + w[13], t5 = w[14] + w[15];         \
    float t6 = w[16] + w[17], t7 = w[18] + w[19], t8 = w[20] + w[21];         \
    float s0 = (((t0 + t1) + (t2 + t3)) + ((t4 + t5) + (t6 + t7))) +          \
               (t8 + w[22]);                                                  \
    a[0] = s0;                                                                \
    s0 += w[23] - w[4];  a[1] = s0;                                           \
    s0 += w[24] - w[5];  a[2] = s0;                                           \
    s0 += w[25] - w[6];  a[3] = s0;                                           \
    s0 += w[26] - w[7];  a[4] = s0;                                           \
    s0 += w[27] - w[8];  a[5] = s0;                                           \
    s0 += w[28] - w[9];  a[6] = s0;                                           \
    s0 += w[29] - w[10]; a[7] = s0;                                           \
    float u4 = w[20] + w[21], u5 = w[22] + w[23], u6 = w[24] + w[25];         \
    float u7 = w[26] + w[27], u8 = w[28] + w[29];                             \
    float s1 = (((t4 + t5) + (t6 + t7)) + ((u4 + u5) + (u6 + u7))) +          \
               (u8 + w[30]);                                                  \
    a[8] = s1;                                                                \
    s1 += w[31] - w[12]; a[9] = s1;                                           \
    s1 += w[32] - w[13]; a[10] = s1;                                          \
    s1 += w[33] - w[14]; a[11] = s1;                                          \
    s1 += w[34] - w[15]; a[12] = s1;                                          \
    s1 += w[35] - w[16]; a[13] = s1;                                          \
    s1 += w[36] - w[17]; a[14] = s1;                                          \
    s1 += w[37] - w[18]; a[15] = s1;                                          \
    float *ao = an + (size_t)(kk)*TD + j0;                                    \
    *(float4 *)(ao) = make_float4(a[0], a[1], a[2], a[3]);                    \
    *(float4 *)(ao + 4) = make_float4(a[4], a[5], a[6], a[7]);                \
    *(float4 *)(ao + 8) = make_float4(a[8], a[9], a[10], a[11]);              \
    *(float4 *)(ao + 12) = make_float4(a[12], a[13], a[14], a[15]);           \
  }

__global__ __launch_bounds__(64) void phase1_softmax(
    const float *__restrict__ cpT, float *__restrict__ aT,
    const float *__restrict__ scores, float *__restrict__ out1) {
  __shared__ __align__(16) float qbuf[1320];  // 66 groups * 20 floats

  if (blockIdx.x >= NB) {
    // ---------------- softmax row (64 threads, float2 path) ----------------
    const int row = blockIdx.x - NB;  // n*TD + j
    const int n = row >> 10;
    const int j = row & 1023;
    const int tid = threadIdx.x;
    const float2 *s2 = (const float2 *)(scores + (size_t)row * TE);
    float2 a0 = s2[tid], a1 = s2[tid + 64], a2 = s2[tid + 128];
    float m = fmaxf(fmaxf(fmaxf(a0.x, a0.y), fmaxf(a1.x, a1.y)),
                    fmaxf(a2.x, a2.y));
#pragma unroll
    for (int off = 32; off; off >>= 1) m = fmaxf(m, __shfl_xor(m, off));
    float e0 = __expf(a0.x - m), e1 = __expf(a0.y - m);
    float e2 = __expf(a1.x - m), e3 = __expf(a1.y - m);
    float e4 = __expf(a2.x - m), e5 = __expf(a2.y - m);
    float sum = ((e0 + e1) + (e2 + e3)) + (e4 + e5);
#pragma unroll
    for (int off = 32; off; off >>= 1) sum += __shfl_xor(sum, off);
    const float r = 1.0f / sum;
    float2 *d2 = (float2 *)(out1 + (size_t)n * (2 * TD * TE) + (size_t)j * TE);
    d2[tid] = make_float2(e0 * r, e1 * r);
    d2[tid + 64] = make_float2(e2 * r, e3 * r);
    d2[tid + 128] = make_float2(e4 * r, e5 * r);
    return;
  }

  // ------------------------- phase-1 scan (1 wave) -------------------------
  const int n = blockIdx.x;
  const int L = threadIdx.x;  // 0..63, one wave
  const int j0 = L * 16;

  // zero the 24-float logical pad (j in [-24,-1] -> J in [0,24))
  if (L < 24) qbuf[P1PH(L)] = 0.f;

  const float *cpn = cpT + (size_t)n * TE * TD;
  float *an = aT + (size_t)n * TE * TD;

  // lane-local LDS pointers (all b128-aligned, conflict-free under swizzle)
  float *w01p = &qbuf[P1PH(j0 + 24)];
  float *w23p = &qbuf[P1PH(j0 + 32)];
  const float *rdA = &qbuf[P1PH(j0) + 4];
  const float *rdB = &qbuf[P1PH(j0 + 16)];

  float a[16];
#pragma unroll
  for (int i = 0; i < 16; ++i) a[i] = 0.f;
  if (L == 0) a[0] = 1.f;

  // prologue: step s uses column max(s-1,0); fill sets for steps 0..4
  float4 cpA0, cpA1, cpA2, cpA3, cpB0, cpB1, cpB2, cpB3;
  float4 cpC0, cpC1, cpC2, cpC3, cpD0, cpD1, cpD2, cpD3;
  float4 cpE0, cpE1, cpE2, cpE3, cpF0, cpF1, cpF2, cpF3;
  {
    const float *p0 = cpn + j0;  // col 0 (steps 0 and 1)
    cpA0 = *(const float4 *)(p0);
    cpA1 = *(const float4 *)(p0 + 4);
    cpA2 = *(const float4 *)(p0 + 8);
    cpA3 = *(const float4 *)(p0 + 12);
    cpB0 = cpA0; cpB1 = cpA1; cpB2 = cpA2; cpB3 = cpA3;
    const float *p1 = cpn + (size_t)1 * TD + j0;  // col 1 (step 2)
    cpC0 = *(const float4 *)(p1);
    cpC1 = *(const float4 *)(p1 + 4);
    cpC2 = *(const float4 *)(p1 + 8);
    cpC3 = *(const float4 *)(p1 + 12);
    const float *p2 = cpn + (size_t)2 * TD + j0;  // col 2 (step 3)
    cpD0 = *(const float4 *)(p2);
    cpD1 = *(const float4 *)(p2 + 4);
    cpD2 = *(const float4 *)(p2 + 8);
    cpD3 = *(const float4 *)(p2 + 12);
    const float *p3 = cpn + (size_t)3 * TD + j0;  // col 3 (step 4)
    cpE0 = *(const float4 *)(p3);
    cpE1 = *(const float4 *)(p3 + 4);
    cpE2 = *(const float4 *)(p3 + 8);
    cpE3 = *(const float4 *)(p3 + 12);
  }

  for (int k = 0; k < TE; k += 6) {  // TE = 384 = 6*64
    P1_BODY(cpA0, cpA1, cpA2, cpA3, cpF0, cpF1, cpF2, cpF3, k);
    P1_BODY(cpB0, cpB1, cpB2, cpB3, cpA0, cpA1, cpA2, cpA3, k + 1);
    P1_BODY(cpC0, cpC1, cpC2, cpC3, cpB0, cpB1, cpB2, cpB3, k + 2);
    P1_BODY(cpD0, cpD1, cpD2, cpD3, cpC0, cpC1, cpC2, cpC3, k + 3);
    P1_BODY(cpE0, cpE1, cpE2, cpE3, cpD0, cpD1, cpD2, cpD3, k + 4);
    P1_BODY(cpF0, cpF1, cpF2, cpF3, cpE0, cpE1, cpE2, cpE3, k + 5);
  }
}

// ---------------------------------------------------------------- phase 2 (B)
__global__ __launch_bounds__(256) void phase2_B(
    const float *__restrict__ cpT, const float *__restrict__ aT,
    float *__restrict__ BT) {
  const int k = blockIdx.x;
  const int n = blockIdx.y;
  const int tid = threadIdx.x;
  const float *cpc = cpT + ((size_t)n * TE + k) * TD;
  const float *ac = aT + ((size_t)n * TE + k) * TD;
  __shared__ float a_l[20 + TD];
  __shared__ float cp_l[TD + 24];
  float4 av = *(const float4 *)(ac + tid * 4);
  *(float4 *)(&a_l[20 + tid * 4]) = av;
  float4 cv = *(const float4 *)(cpc + tid * 4);
  if (tid == 255) cv.w = 0.f;  // cp[1023] never contributes (clamp rule)
  *(float4 *)(&cp_l[tid * 4]) = cv;
  if (tid < 20) a_l[tid] = 0.f;
  if (tid < 24) cp_l[TD + tid] = 0.f;
  __syncthreads();
  const int j0 = tid * 4;
  float ar[21], cpr[21];
#pragma unroll
  for (int t = 0; t < 21; ++t) ar[t] = a_l[20 + j0 - 19 + t];
#pragma unroll
  for (int t = 0; t < 21; ++t) cpr[t] = cp_l[j0 + t];
  float Bo[4];
#pragma unroll
  for (int i = 0; i < 4; ++i) {
    float W = 0.f, acc2 = 0.f;
#pragma unroll
    for (int d = 19; d >= 2; --d) {
      W += cpr[i + 19 - d];
      acc2 = fmaf(ar[19 + i - d], W, acc2);
    }
    Bo[i] = acc2;
  }
  *(float4 *)(BT + ((size_t)n * TE + k) * TD + j0) =
      make_float4(Bo[0], Bo[1], Bo[2], Bo[3]);
}

// ---------------------------------------------------------------- transpose (+ bf16 copy)
__global__ __launch_bounds__(256) void transpose_B(
    const float *__restrict__ BT, float *__restrict__ out1,
    ushort *__restrict__ Bh) {
  __shared__ float tile[32][33];
  const int n = blockIdx.z;
  const int k0 = blockIdx.x * 32;
  const int j0 = blockIdx.y * 32;
  const int tx = threadIdx.x & 31;
  const int ty = threadIdx.x >> 5;  // 0..7
  const float *src = BT + (size_t)n * TE * TD;
#pragma unroll
  for (int r = 0; r < 4; ++r) {
    const int kk = ty + r * 8;
    tile[kk][tx] = src[(size_t)(k0 + kk) * TD + j0 + tx];
  }
  __syncthreads();
  float *dst = out1 + (size_t)n * (2 * TD * TE) + (size_t)TD * TE;
#pragma unroll
  for (int r = 0; r < 4; ++r) {
    const int jj = ty + r * 8;
    const float val = tile[tx][jj];
    dst[(size_t)(j0 + jj) * TE + k0 + tx] = val;
    Bh[((size_t)n * TD + j0 + jj) * TE + k0 + tx] = f2bf(val);
  }
}

// ---------------------------------------------------------------- launch
extern "C" void kernel_launch(void *const *d_in, const int *in_sizes, int n_in,
                              void *d_out, int out_size, void *d_ws,
                              size_t ws_size, hipStream_t stream) {
  (void)in_sizes; (void)n_in; (void)out_size; (void)ws_size;
  const float *enc = (const float *)d_in[0];  // [32][384][512]
  const float *mel = (const float *)d_in[1];  // [32][1024][512]
  float *out = (float *)d_out;
  float *out0 = out;                         // att_out [32][1024][512]
  float *out1 = out + (size_t)NB * TD * DM;  // stacked [32][2][1024][384]

  const size_t SZ = (size_t)NB * TD * TE;    // 12,582,912 floats
  float *ws = (float *)d_ws;
  float *ws_scores = ws;       // scores [n][j][k]; later BT
  float *ws_cpT = ws + SZ;     // cond_prob [n][k][j] (holds ench+melh before)
  float *ws_aT = ws + 2 * SZ;  // a [n][k][j] (holds Bh after phase2)
  ushort *encTb = (ushort *)(ws + 3 * SZ + NB * TE);  // encT bf16 [n][d][k]
  ushort *ench = (ushort *)ws_cpT;                    // bf16 [n][k][d]
  ushort *melh = (ushort *)ws_cpT + (size_t)NB * TE * DM;  // bf16 [n][j][d]
  ushort *Bh = (ushort *)ws_aT;                       // bf16 [n][j][k]
  float *ws_BT = ws_scores;

  conv_bf16<<<(NB * TD * DM) / (256 * 8), 256, 0, stream>>>(mel, melh);
  conv_encT<<<dim3(DM / 32, TE / 32, NB), 256, 0, stream>>>(enc, ench, encTb);
  gemm_bf16_mfma<<<dim3(TE / 128, TD / 128, NB), 256, 0, stream>>>(
      melh, ench, ws_scores, DM, TE, (size_t)TD * DM, (size_t)TE * DM,
      (size_t)TD * TE, 0.0441941738241592f);
  cond_prob2<<<dim3(TE / 64, TD / 64, NB), 256, 0, stream>>>(ws_scores, ws_cpT);
  phase1_softmax<<<NB + NB * TD, 64, 0, stream>>>(ws_cpT, ws_aT, ws_scores,
                                                  out1);
  phase2_B<<<dim3(TE, NB), 256, 0, stream>>>(ws_cpT, ws_aT, ws_BT);
  transpose_B<<<dim3(TE / 32, TD / 32, NB), 256, 0, stream>>>(ws_BT, out1, Bh);
  gemm_bf16_mfma<<<dim3(DM / 128, TD / 128, NB), 256, 0, stream>>>(
      Bh, encTb, out0, TE, DM, (size_t)TD * TE, (size_t)DM * TE,
      (size_t)TD * DM, 1.0f);
}

// Round 8
// 489.325 us; speedup vs baseline: 1.1243x; 1.0180x over previous
//
#include <hip/hip_runtime.h>
#include <hip/hip_bf16.h>

// MoBoAlignerAttention on MI355X — round 10 (resubmit; round-10 bench was an
// infra failure, no GPU data). Change vs round 9 (phase1 scan only): the LDS
// q-exchange is replaced by a pure-register DPP exchange. Lane L needs
// q[j0-20..j0-1] = lane L-1's 16 q values + lane L-2's top 4.
// v_mov_b32_dpp wave_shr:1 (ctrl 0x138, bound_ctrl=1 -> lane 0 reads 0 =
// the zero pad) delivers both: 16 shifts for L-1, +4 shifts of the shifted
// top quad for L-2. Removes ALL DS ops, fences, and LDS latency from the
// 384-step serial loop. Window math, stores, cp prefetch (depth 5)
// bit-identical to round 9.
//
// Pipeline:
//  conv_bf16     : mel f32 -> melh bf16 [n][j][d]
//  conv_encT     : enc f32 -> ench bf16 [n][k][d]  +  encT bf16 [n][d][k]
//  gemm_mfma     : scores = melh @ ench^T / sqrt(512)        (bf16 MFMA)
//  cond_prob2    : T inline (threefry); cp = e/(window_19(e)+1e-8) -> cpT
//  phase1_softmax: scan a_k (32 blocks) || softmax -> out1 (32768 blocks)
//  phase2_B      : B[j,k] = sum_{d=2..19} a[j-d,k]*W_{20-d}(j,k)
//  transpose_B   : BT -> d_out B slot (f32) + Bh bf16 [n][j][k]
//  gemm_mfma     : att = Bh @ encT^T                         (bf16 MFMA)

#define NB 32
#define TD 1024
#define TE 384
#define DM 512

typedef __attribute__((ext_vector_type(8))) short bf16x8;
typedef __attribute__((ext_vector_type(4))) float f32x4;

#define GLDS16(g, l)                                                          \
  __builtin_amdgcn_global_load_lds(                                           \
      (const __attribute__((address_space(1))) unsigned int *)(g),            \
      (__attribute__((address_space(3))) unsigned int *)(l), 16, 0, 0)

// lane L gets lane L-1's value; lane 0 gets 0 (bound_ctrl) == zero pad
#define DPP_SHR1(x)                                                           \
  __int_as_float(__builtin_amdgcn_update_dpp(0, __float_as_int(x), 0x138,     \
                                             0xF, 0xF, true))

// f32 -> bf16 round-to-nearest-even
__device__ __forceinline__ ushort f2bf(float f) {
  unsigned u = __float_as_uint(f);
  return (ushort)((u + 0x7FFFu + ((u >> 16) & 1u)) >> 16);
}

// ---------------------------------------------------------------- threefry
__device__ __forceinline__ void tf_round(unsigned &x0, unsigned &x1, int r) {
  x0 += x1;
  x1 = (x1 << r) | (x1 >> (32 - r));
  x1 ^= x0;
}

__device__ __forceinline__ void threefry2x32(unsigned c0, unsigned c1,
                                             unsigned &o0, unsigned &o1) {
  const unsigned k0 = 0u, k1 = 1234u;
  const unsigned k2 = 0u ^ 1234u ^ 0x1BD11BDAu;
  unsigned x0 = c0 + k0, x1 = c1 + k1;
  tf_round(x0, x1, 13); tf_round(x0, x1, 15); tf_round(x0, x1, 26); tf_round(x0, x1, 6);
  x0 += k1; x1 += k2 + 1u;
  tf_round(x0, x1, 17); tf_round(x0, x1, 29); tf_round(x0, x1, 16); tf_round(x0, x1, 24);
  x0 += k2; x1 += k0 + 2u;
  tf_round(x0, x1, 13); tf_round(x0, x1, 15); tf_round(x0, x1, 26); tf_round(x0, x1, 6);
  x0 += k0; x1 += k1 + 3u;
  tf_round(x0, x1, 17); tf_round(x0, x1, 29); tf_round(x0, x1, 16); tf_round(x0, x1, 24);
  x0 += k1; x1 += k2 + 4u;
  tf_round(x0, x1, 13); tf_round(x0, x1, 15); tf_round(x0, x1, 26); tf_round(x0, x1, 6);
  x0 += k2; x1 += k0 + 5u;
  o0 = x0; o1 = x1;
}

__device__ __forceinline__ float tf_uniform(unsigned bits) {
  return __uint_as_float((bits >> 9) | 0x3F800000u) - 1.0f;
}

// ---------------------------------------------------------------- f32 -> bf16 (8 elems/thread)
__global__ __launch_bounds__(256) void conv_bf16(const float *__restrict__ src,
                                                 ushort *__restrict__ dst) {
  const size_t i = ((size_t)blockIdx.x * 256 + threadIdx.x) * 8;
  float4 a = *(const float4 *)(src + i);
  float4 b = *(const float4 *)(src + i + 4);
  uint4 o;
  o.x = (unsigned)f2bf(a.x) | ((unsigned)f2bf(a.y) << 16);
  o.y = (unsigned)f2bf(a.z) | ((unsigned)f2bf(a.w) << 16);
  o.z = (unsigned)f2bf(b.x) | ((unsigned)f2bf(b.y) << 16);
  o.w = (unsigned)f2bf(b.z) | ((unsigned)f2bf(b.w) << 16);
  *(uint4 *)(dst + i) = o;
}

// ---------------------------------------------------------------- enc -> ench + encT
__global__ __launch_bounds__(256) void conv_encT(const float *__restrict__ enc,
                                                 ushort *__restrict__ ench,
                                                 ushort *__restrict__ encT) {
  const int n = blockIdx.z;
  const int d0 = blockIdx.x * 32;
  const int k0 = blockIdx.y * 32;
  __shared__ ushort t[32][33];
  const int row = threadIdx.x >> 3;      // k within tile
  const int c4 = (threadIdx.x & 7) * 4;  // d within tile
  float4 v = *(const float4 *)(enc + ((size_t)n * TE + k0 + row) * DM + d0 + c4);
  ushort4 e;
  e.x = f2bf(v.x); e.y = f2bf(v.y); e.z = f2bf(v.z); e.w = f2bf(v.w);
  t[row][c4 + 0] = e.x; t[row][c4 + 1] = e.y;
  t[row][c4 + 2] = e.z; t[row][c4 + 3] = e.w;
  *(ushort4 *)(ench + ((size_t)n * TE + k0 + row) * DM + d0 + c4) = e;
  __syncthreads();
  const int dr = threadIdx.x >> 3;       // d within tile
  const int kc = (threadIdx.x & 7) * 4;  // k within tile
  ushort4 o;
  o.x = t[kc + 0][dr]; o.y = t[kc + 1][dr];
  o.z = t[kc + 2][dr]; o.w = t[kc + 3][dr];
  *(ushort4 *)(encT + ((size_t)n * DM + d0 + dr) * TE + k0 + kc) = o;
}

// ---------------------------------------------------------------- bf16 MFMA GEMM
// C[m][n] = scale * sum_k A[m][k]*B[n][k]   (both operands K-contiguous)
// 128x128 tile, 4 waves (2x2), each wave 4x4 16x16x32 MFMA tiles, BK=32.
// Staging via global_load_lds width=16 (m97 pattern).
__global__ __launch_bounds__(256) void gemm_bf16_mfma(
    const ushort *__restrict__ Ag, const ushort *__restrict__ Bg,
    float *__restrict__ Cg, int K, int N, size_t sA, size_t sB, size_t sC,
    float scale) {
  const int nb = blockIdx.z;
  const int n0 = blockIdx.x * 128;
  const int m0 = blockIdx.y * 128;
  const int tid = threadIdx.x;
  const int wave = tid >> 6, lane = tid & 63;
  const int wm = (wave >> 1) * 64, wn = (wave & 1) * 64;
  const int fr = lane & 15, quad = lane >> 4;
  const ushort *A = Ag + nb * sA + (size_t)m0 * K;
  const ushort *B = Bg + nb * sB + (size_t)n0 * K;
  __shared__ __align__(16) ushort As[128 * 32];
  __shared__ __align__(16) ushort Bs[128 * 32];
  f32x4 acc[4][4];
#pragma unroll
  for (int i = 0; i < 4; ++i)
#pragma unroll
    for (int c = 0; c < 4; ++c) acc[i][c] = (f32x4){0.f, 0.f, 0.f, 0.f};

  const int r0 = 32 * wave + (lane >> 2);  // global row this lane feeds
  const int c0 = (lane & 3) * 8;           // ushort chunk within the row
  const ushort *gA0 = A + (size_t)r0 * K + c0;
  const ushort *gA1 = A + (size_t)(r0 + 16) * K + c0;
  const ushort *gB0 = B + (size_t)r0 * K + c0;
  const ushort *gB1 = B + (size_t)(r0 + 16) * K + c0;
  ushort *lA0 = &As[(32 * wave) * 32];
  ushort *lA1 = &As[(32 * wave + 16) * 32];
  ushort *lB0 = &Bs[(32 * wave) * 32];
  ushort *lB1 = &Bs[(32 * wave + 16) * 32];

  for (int kb = 0; kb < K; kb += 32) {
    __syncthreads();  // prior compute finished reading LDS
    GLDS16(gA0 + kb, lA0);
    GLDS16(gA1 + kb, lA1);
    GLDS16(gB0 + kb, lB0);
    GLDS16(gB1 + kb, lB1);
    __syncthreads();  // compiler drains vmcnt before barrier -> data ready
    bf16x8 af[4], bfv[4];
#pragma unroll
    for (int i = 0; i < 4; ++i)
      af[i] = *(const bf16x8 *)(&As[(wm + i * 16 + fr) * 32 + quad * 8]);
#pragma unroll
    for (int c = 0; c < 4; ++c)
      bfv[c] = *(const bf16x8 *)(&Bs[(wn + c * 16 + fr) * 32 + quad * 8]);
#pragma unroll
    for (int i = 0; i < 4; ++i)
#pragma unroll
      for (int c = 0; c < 4; ++c)
        acc[i][c] = __builtin_amdgcn_mfma_f32_16x16x32_bf16(af[i], bfv[c],
                                                            acc[i][c], 0, 0, 0);
  }
  float *Cb = Cg + nb * sC;
#pragma unroll
  for (int i = 0; i < 4; ++i)
#pragma unroll
    for (int c = 0; c < 4; ++c)
#pragma unroll
      for (int r = 0; r < 4; ++r)
        Cb[(size_t)(m0 + wm + i * 16 + quad * 4 + r) * N + n0 + wn + c * 16 + fr] =
            acc[i][c][r] * scale;
}

// ---------------------------------------------------------------- cond_prob (parallel, T inline)
__global__ __launch_bounds__(256) void cond_prob2(
    const float *__restrict__ scores, float *__restrict__ cpT) {
  const int n = blockIdx.z;
  const int j0 = blockIdx.y * 64;
  const int k0 = blockIdx.x * 64;
  const int tid = threadIdx.x;
  __shared__ float eL[82][65];
  __shared__ float Tl[64];

  if (tid < 64) {
    unsigned o0, o1;
    threefry2x32(0u, (unsigned)(n * TE + k0 + tid), o0, o1);
    Tl[tid] = tf_uniform(o0 ^ o1) + 0.5f;  // T = u*(1.5-0.5)+0.5
  }
  __syncthreads();

  {
    const int c4 = (tid & 15) * 4;
    const int r0 = tid >> 4;  // 0..15
    const float it0 = 1.0f / Tl[c4 + 0], it1 = 1.0f / Tl[c4 + 1],
                it2 = 1.0f / Tl[c4 + 2], it3 = 1.0f / Tl[c4 + 3];
#pragma unroll
    for (int p = 0; p < 6; ++p) {
      const int r = r0 + p * 16;
      if (r < 82) {
        const int j = j0 + r;
        float4 s;
        if (j < TD) {
          s = *(const float4 *)(scores + ((size_t)n * TD + j) * TE + k0 + c4);
          s.x = __expf(s.x * it0); s.y = __expf(s.y * it1);
          s.z = __expf(s.z * it2); s.w = __expf(s.w * it3);
        } else {
          s = make_float4(0.f, 0.f, 0.f, 0.f);
        }
        eL[r][c4 + 0] = s.x; eL[r][c4 + 1] = s.y;
        eL[r][c4 + 2] = s.z; eL[r][c4 + 3] = s.w;
      }
    }
  }
  __syncthreads();

  const int k = tid & 63;
  const int jl0 = (tid >> 6) * 16;
  float e_r[35];
#pragma unroll
  for (int t = 0; t < 35; ++t) e_r[t] = eL[jl0 + t][k];
  float win = 0.f;
#pragma unroll
  for (int t = 15; t <= 33; ++t) win += e_r[t];
  float cp[16];
#pragma unroll
  for (int jl = 15; jl >= 0; --jl) {
    cp[jl] = e_r[jl] / (win + 1e-8f);
    if (jl > 0) win += e_r[jl - 1] - e_r[jl + 18];
  }
  float *dst = cpT + ((size_t)n * TE + k0 + k) * TD + j0 + jl0;
#pragma unroll
  for (int q = 0; q < 4; ++q)
    *(float4 *)(dst + q * 4) =
        make_float4(cp[q * 4], cp[q * 4 + 1], cp[q * 4 + 2], cp[q * 4 + 3]);
}

// ---------------------------------------------------------------- phase 1 scan + softmax (fused)
// Blocks 0..NB-1: DPP-exchange wave-synchronous scan (no LDS, no DS ops).
// Blocks NB..NB+NB*TD-1: one softmax row each (64 threads, no LDS).

#define P1_BODY(CU0, CU1, CU2, CU3, CL0, CL1, CL2, CL3, kk)                   \
  {                                                                           \
    /* prefetch cp column used at step (kk)+5 (column shift: col(k)=k-1) */   \
    const int pc = ((kk) + 4 < TE) ? ((kk) + 4) : (TE - 1);                   \
    const float *pp = cpn + (size_t)pc * TD + j0;                             \
    CL0 = *(const float4 *)(pp);                                              \
    CL1 = *(const float4 *)(pp + 4);                                          \
    CL2 = *(const float4 *)(pp + 8);                                          \
    CL3 = *(const float4 *)(pp + 12);                                         \
    const float q0 = a[0] * CU0.x, q1 = a[1] * CU0.y;                         \
    const float q2 = a[2] * CU0.z, q3 = a[3] * CU0.w;                         \
    const float q4 = a[4] * CU1.x, q5 = a[5] * CU1.y;                         \
    const float q6 = a[6] * CU1.z, q7 = a[7] * CU1.w;                         \
    const float q8 = a[8] * CU2.x, q9 = a[9] * CU2.y;                         \
    const float q10 = a[10] * CU2.z, q11 = a[11] * CU2.w;                     \
    const float q12 = a[12] * CU3.x, q13 = a[13] * CU3.y;                     \
    const float q14 = a[14] * CU3.z, q15 = a[15] * CU3.w;                     \
    /* halo via DPP: m_i = lane L-1's q_i ; p_i = lane L-2's q_{12+i} */      \
    const float m0 = DPP_SHR1(q0), m1 = DPP_SHR1(q1);                         \
    const float m2 = DPP_SHR1(q2), m3 = DPP_SHR1(q3);                         \
    const float m4 = DPP_SHR1(q4), m5 = DPP_SHR1(q5);                         \
    const float m6 = DPP_SHR1(q6), m7 = DPP_SHR1(q7);                         \
    const float m8 = DPP_SHR1(q8), m9 = DPP_SHR1(q9);                         \
    const float m10 = DPP_SHR1(q10), m11 = DPP_SHR1(q11);                     \
    const float m12 = DPP_SHR1(q12), m13 = DPP_SHR1(q13);                     \
    const float m14 = DPP_SHR1(q14), m15 = DPP_SHR1(q15);                     \
    const float p0 = DPP_SHR1(m12), p1 = DPP_SHR1(m13);                       \
    const float p2 = DPP_SHR1(m14), p3 = DPP_SHR1(m15);                       \
    float w[38];                                                              \
    w[4] = p0;   w[5] = p1;   w[6] = p2;   w[7] = p3;                         \
    w[8] = m0;   w[9] = m1;   w[10] = m2;  w[11] = m3;                        \
    w[12] = m4;  w[13] = m5;  w[14] = m6;  w[15] = m7;                        \
    w[16] = m8;  w[17] = m9;  w[18] = m10; w[19] = m11;                       \
    w[20] = m12; w[21] = m13; w[22] = m14; w[23] = m15;                       \
    w[24] = q0;  w[25] = q1;  w[26] = q2;  w[27] = q3;                        \
    w[28] = q4;  w[29] = q5;  w[30] = q6;  w[31] = q7;                        \
    w[32] = q8;  w[33] = q9;  w[34] = q10; w[35] = q11;                       \
    w[36] = q12; w[37] = q13;                                                 \
    /* window for j=j0+i is sum w[i+4 .. i+22]; two balanced trees + slides */\
    float t0 = w[4] + w[5], t1 = w[6] + w[7], t2 = w[8] + w[9];               \
    float t3 = w[10] + w[11], t4 = w[12] + w[13], t5 = w[14] + w[15];         \
    float t6 = w[16] + w[17], t7 = w[18] + w[19], t8 = w[20] + w[21];         \
    float s0 = (((t0 + t1) + (t2 + t3)) + ((t4 + t5) + (t6 + t7))) +          \
               (t8 + w[22]);                                                  \
    a[0] = s0;                                                                \
    s0 += w[23] - w[4];  a[1] = s0;                                           \
    s0 += w[24] - w[5];  a[2] = s0;                                           \
    s0 += w[25] - w[6];  a[3] = s0;                                           \
    s0 += w[26] - w[7];  a[4] = s0;                                           \
    s0 += w[27] - w[8];  a[5] = s0;                                           \
    s0 += w[28] - w[9];  a[6] = s0;                                           \
    s0 += w[29] - w[10]; a[7] = s0;                                           \
    float u4 = w[20] + w[21], u5 = w[22] + w[23], u6 = w[24] + w[25];         \
    float u7 = w[26] + w[27], u8 = w[28] + w[29];                             \
    float s1 = (((t4 + t5) + (t6 + t7)) + ((u4 + u5) + (u6 + u7))) +          \
               (u8 + w[30]);                                                  \
    a[8] = s1;                                                                \
    s1 += w[31] - w[12]; a[9] = s1;                                           \
    s1 += w[32] - w[13]; a[10] = s1;                                          \
    s1 += w[33] - w[14]; a[11] = s1;                                          \
    s1 += w[34] - w[15]; a[12] = s1;                                          \
    s1 += w[35] - w[16]; a[13] = s1;                                          \
    s1 += w[36] - w[17]; a[14] = s1;                                          \
    s1 += w[37] - w[18]; a[15] = s1;                                          \
    float *ao = an + (size_t)(kk)*TD + j0;                                    \
    *(float4 *)(ao) = make_float4(a[0], a[1], a[2], a[3]);                    \
    *(float4 *)(ao + 4) = make_float4(a[4], a[5], a[6], a[7]);                \
    *(float4 *)(ao + 8) = make_float4(a[8], a[9], a[10], a[11]);              \
    *(float4 *)(ao + 12) = make_float4(a[12], a[13], a[14], a[15]);           \
  }

__global__ __launch_bounds__(64) void phase1_softmax(
    const float *__restrict__ cpT, float *__restrict__ aT,
    const float *__restrict__ scores, float *__restrict__ out1) {
  if (blockIdx.x >= NB) {
    // ---------------- softmax row (64 threads, float2 path) ----------------
    const int row = blockIdx.x - NB;  // n*TD + j
    const int n = row >> 10;
    const int j = row & 1023;
    const int tid = threadIdx.x;
    const float2 *s2 = (const float2 *)(scores + (size_t)row * TE);
    float2 a0 = s2[tid], a1 = s2[tid + 64], a2 = s2[tid + 128];
    float m = fmaxf(fmaxf(fmaxf(a0.x, a0.y), fmaxf(a1.x, a1.y)),
                    fmaxf(a2.x, a2.y));
#pragma unroll
    for (int off = 32; off; off >>= 1) m = fmaxf(m, __shfl_xor(m, off));
    float e0 = __expf(a0.x - m), e1 = __expf(a0.y - m);
    float e2 = __expf(a1.x - m), e3 = __expf(a1.y - m);
    float e4 = __expf(a2.x - m), e5 = __expf(a2.y - m);
    float sum = ((e0 + e1) + (e2 + e3)) + (e4 + e5);
#pragma unroll
    for (int off = 32; off; off >>= 1) sum += __shfl_xor(sum, off);
    const float r = 1.0f / sum;
    float2 *d2 = (float2 *)(out1 + (size_t)n * (2 * TD * TE) + (size_t)j * TE);
    d2[tid] = make_float2(e0 * r, e1 * r);
    d2[tid + 64] = make_float2(e2 * r, e3 * r);
    d2[tid + 128] = make_float2(e4 * r, e5 * r);
    return;
  }

  // ------------------------- phase-1 scan (1 wave) -------------------------
  const int n = blockIdx.x;
  const int L = threadIdx.x;  // 0..63, one wave
  const int j0 = L * 16;

  const float *cpn = cpT + (size_t)n * TE * TD;
  float *an = aT + (size_t)n * TE * TD;

  float a[16];
#pragma unroll
  for (int i = 0; i < 16; ++i) a[i] = 0.f;
  if (L == 0) a[0] = 1.f;

  // prologue: step s uses column max(s-1,0); fill sets for steps 0..4
  float4 cpA0, cpA1, cpA2, cpA3, cpB0, cpB1, cpB2, cpB3;
  float4 cpC0, cpC1, cpC2, cpC3, cpD0, cpD1, cpD2, cpD3;
  float4 cpE0, cpE1, cpE2, cpE3, cpF0, cpF1, cpF2, cpF3;
  {
    const float *p0 = cpn + j0;  // col 0 (steps 0 and 1)
    cpA0 = *(const float4 *)(p0);
    cpA1 = *(const float4 *)(p0 + 4);
    cpA2 = *(const float4 *)(p0 + 8);
    cpA3 = *(const float4 *)(p0 + 12);
    cpB0 = cpA0; cpB1 = cpA1; cpB2 = cpA2; cpB3 = cpA3;
    const float *p1 = cpn + (size_t)1 * TD + j0;  // col 1 (step 2)
    cpC0 = *(const float4 *)(p1);
    cpC1 = *(const float4 *)(p1 + 4);
    cpC2 = *(const float4 *)(p1 + 8);
    cpC3 = *(const float4 *)(p1 + 12);
    const float *p2 = cpn + (size_t)2 * TD + j0;  // col 2 (step 3)
    cpD0 = *(const float4 *)(p2);
    cpD1 = *(const float4 *)(p2 + 4);
    cpD2 = *(const float4 *)(p2 + 8);
    cpD3 = *(const float4 *)(p2 + 12);
    const float *p3 = cpn + (size_t)3 * TD + j0;  // col 3 (step 4)
    cpE0 = *(const float4 *)(p3);
    cpE1 = *(const float4 *)(p3 + 4);
    cpE2 = *(const float4 *)(p3 + 8);
    cpE3 = *(const float4 *)(p3 + 12);
  }

  for (int k = 0; k < TE; k += 6) {  // TE = 384 = 6*64
    P1_BODY(cpA0, cpA1, cpA2, cpA3, cpF0, cpF1, cpF2, cpF3, k);
    P1_BODY(cpB0, cpB1, cpB2, cpB3, cpA0, cpA1, cpA2, cpA3, k + 1);
    P1_BODY(cpC0, cpC1, cpC2, cpC3, cpB0, cpB1, cpB2, cpB3, k + 2);
    P1_BODY(cpD0, cpD1, cpD2, cpD3, cpC0, cpC1, cpC2, cpC3, k + 3);
    P1_BODY(cpE0, cpE1, cpE2, cpE3, cpD0, cpD1, cpD2, cpD3, k + 4);
    P1_BODY(cpF0, cpF1, cpF2, cpF3, cpE0, cpE1, cpE2, cpE3, k + 5);
  }
}

// ---------------------------------------------------------------- phase 2 (B)
__global__ __launch_bounds__(256) void phase2_B(
    const float *__restrict__ cpT, const float *__restrict__ aT,
    float *__restrict__ BT) {
  const int k = blockIdx.x;
  const int n = blockIdx.y;
  const int tid = threadIdx.x;
  const float *cpc = cpT + ((size_t)n * TE + k) * TD;
  const float *ac = aT + ((size_t)n * TE + k) * TD;
  __shared__ float a_l[20 + TD];
  __shared__ float cp_l[TD + 24];
  float4 av = *(const float4 *)(ac + tid * 4);
  *(float4 *)(&a_l[20 + tid * 4]) = av;
  float4 cv = *(const float4 *)(cpc + tid * 4);
  if (tid == 255) cv.w = 0.f;  // cp[1023] never contributes (clamp rule)
  *(float4 *)(&cp_l[tid * 4]) = cv;
  if (tid < 20) a_l[tid] = 0.f;
  if (tid < 24) cp_l[TD + tid] = 0.f;
  __syncthreads();
  const int j0 = tid * 4;
  float ar[21], cpr[21];
#pragma unroll
  for (int t = 0; t < 21; ++t) ar[t] = a_l[20 + j0 - 19 + t];
#pragma unroll
  for (int t = 0; t < 21; ++t) cpr[t] = cp_l[j0 + t];
  float Bo[4];
#pragma unroll
  for (int i = 0; i < 4; ++i) {
    float W = 0.f, acc2 = 0.f;
#pragma unroll
    for (int d = 19; d >= 2; --d) {
      W += cpr[i + 19 - d];
      acc2 = fmaf(ar[19 + i - d], W, acc2);
    }
    Bo[i] = acc2;
  }
  *(float4 *)(BT + ((size_t)n * TE + k) * TD + j0) =
      make_float4(Bo[0], Bo[1], Bo[2], Bo[3]);
}

// ---------------------------------------------------------------- transpose (+ bf16 copy)
__global__ __launch_bounds__(256) void transpose_B(
    const float *__restrict__ BT, float *__restrict__ out1,
    ushort *__restrict__ Bh) {
  __shared__ float tile[32][33];
  const int n = blockIdx.z;
  const int k0 = blockIdx.x * 32;
  const int j0 = blockIdx.y * 32;
  const int tx = threadIdx.x & 31;
  const int ty = threadIdx.x >> 5;  // 0..7
  const float *src = BT + (size_t)n * TE * TD;
#pragma unroll
  for (int r = 0; r < 4; ++r) {
    const int kk = ty + r * 8;
    tile[kk][tx] = src[(size_t)(k0 + kk) * TD + j0 + tx];
  }
  __syncthreads();
  float *dst = out1 + (size_t)n * (2 * TD * TE) + (size_t)TD * TE;
#pragma unroll
  for (int r = 0; r < 4; ++r) {
    const int jj = ty + r * 8;
    const float val = tile[tx][jj];
    dst[(size_t)(j0 + jj) * TE + k0 + tx] = val;
    Bh[((size_t)n * TD + j0 + jj) * TE + k0 + tx] = f2bf(val);
  }
}

// ---------------------------------------------------------------- launch
extern "C" void kernel_launch(void *const *d_in, const int *in_sizes, int n_in,
                              void *d_out, int out_size, void *d_ws,
                              size_t ws_size, hipStream_t stream) {
  (void)in_sizes; (void)n_in; (void)out_size; (void)ws_size;
  const float *enc = (const float *)d_in[0];  // [32][384][512]
  const float *mel = (const float *)d_in[1];  // [32][1024][512]
  float *out = (float *)d_out;
  float *out0 = out;                         // att_out [32][1024][512]
  float *out1 = out + (size_t)NB * TD * DM;  // stacked [32][2][1024][384]

  const size_t SZ = (size_t)NB * TD * TE;    // 12,582,912 floats
  float *ws = (float *)d_ws;
  float *ws_scores = ws;       // scores [n][j][k]; later BT
  float *ws_cpT = ws + SZ;     // cond_prob [n][k][j] (holds ench+melh before)
  float *ws_aT = ws + 2 * SZ;  // a [n][k][j] (holds Bh after phase2)
  ushort *encTb = (ushort *)(ws + 3 * SZ + NB * TE);  // encT bf16 [n][d][k]
  ushort *ench = (ushort *)ws_cpT;                    // bf16 [n][k][d]
  ushort *melh = (ushort *)ws_cpT + (size_t)NB * TE * DM;  // bf16 [n][j][d]
  ushort *Bh = (ushort *)ws_aT;                       // bf16 [n][j][k]
  float *ws_BT = ws_scores;

  conv_bf16<<<(NB * TD * DM) / (256 * 8), 256, 0, stream>>>(mel, melh);
  conv_encT<<<dim3(DM / 32, TE / 32, NB), 256, 0, stream>>>(enc, ench, encTb);
  gemm_bf16_mfma<<<dim3(TE / 128, TD / 128, NB), 256, 0, stream>>>(
      melh, ench, ws_scores, DM, TE, (size_t)TD * DM, (size_t)TE * DM,
      (size_t)TD * TE, 0.0441941738241592f);
  cond_prob2<<<dim3(TE / 64, TD / 64, NB), 256, 0, stream>>>(ws_scores, ws_cpT);
  phase1_softmax<<<NB + NB * TD, 64, 0, stream>>>(ws_cpT, ws_aT, ws_scores,
                                                  out1);
  phase2_B<<<dim3(TE, NB), 256, 0, stream>>>(ws_cpT, ws_aT, ws_BT);
  transpose_B<<<dim3(TE / 32, TD / 32, NB), 256, 0, stream>>>(ws_BT, out1, Bh);
  gemm_bf16_mfma<<<dim3(DM / 128, TD / 128, NB), 256, 0, stream>>>(
      Bh, encTb, out0, TE, DM, (size_t)TD * TE, (size_t)DM * TE,
      (size_t)TD * DM, 1.0f);
}

// Round 9
// 473.561 us; speedup vs baseline: 1.1617x; 1.0333x over previous
//
#include <hip/hip_runtime.h>
#include <hip/hip_bf16.h>

// MoBoAlignerAttention on MI355X — round 11.
// Change vs round 10: phase2_B + transpose_B merged into one kernel
// (phase2t). It computes B[j,k] directly from aT/cpT in 64k x 64j tiles
// (LDS-staged, stride-85 conflict-free) and writes BOTH final layouts
// (out1 f32 [j][k] and Bh bf16 [j][k]) via an in-LDS transpose. This
// removes the 48MB BT write + 48MB BT read + one launch. Inner d-loop and
// boundary semantics copied verbatim from phase2_B -> bit-identical.
// Bh relocated to the (dead) ws_scores region to avoid aliasing aT.
//
// Pipeline:
//  conv_bf16     : mel f32 -> melh bf16 [n][j][d]
//  conv_encT     : enc f32 -> ench bf16 [n][k][d]  +  encT bf16 [n][d][k]
//  gemm_mfma     : scores = melh @ ench^T / sqrt(512)        (bf16 MFMA)
//  cond_prob2    : T inline (threefry); cp = e/(window_19(e)+1e-8) -> cpT
//  phase1_softmax: scan a_k (32 blocks, DPP) || softmax (32768 blocks)
//  phase2t       : B tile compute + dual-layout write (f32 + bf16)
//  gemm_mfma     : att = Bh @ encT^T                         (bf16 MFMA)

#define NB 32
#define TD 1024
#define TE 384
#define DM 512

typedef __attribute__((ext_vector_type(8))) short bf16x8;
typedef __attribute__((ext_vector_type(4))) float f32x4;

#define GLDS16(g, l)                                                          \
  __builtin_amdgcn_global_load_lds(                                           \
      (const __attribute__((address_space(1))) unsigned int *)(g),            \
      (__attribute__((address_space(3))) unsigned int *)(l), 16, 0, 0)

// lane L gets lane L-1's value; lane 0 gets 0 (bound_ctrl) == zero pad
#define DPP_SHR1(x)                                                           \
  __int_as_float(__builtin_amdgcn_update_dpp(0, __float_as_int(x), 0x138,     \
                                             0xF, 0xF, true))

// f32 -> bf16 round-to-nearest-even
__device__ __forceinline__ ushort f2bf(float f) {
  unsigned u = __float_as_uint(f);
  return (ushort)((u + 0x7FFFu + ((u >> 16) & 1u)) >> 16);
}

// ---------------------------------------------------------------- threefry
__device__ __forceinline__ void tf_round(unsigned &x0, unsigned &x1, int r) {
  x0 += x1;
  x1 = (x1 << r) | (x1 >> (32 - r));
  x1 ^= x0;
}

__device__ __forceinline__ void threefry2x32(unsigned c0, unsigned c1,
                                             unsigned &o0, unsigned &o1) {
  const unsigned k0 = 0u, k1 = 1234u;
  const unsigned k2 = 0u ^ 1234u ^ 0x1BD11BDAu;
  unsigned x0 = c0 + k0, x1 = c1 + k1;
  tf_round(x0, x1, 13); tf_round(x0, x1, 15); tf_round(x0, x1, 26); tf_round(x0, x1, 6);
  x0 += k1; x1 += k2 + 1u;
  tf_round(x0, x1, 17); tf_round(x0, x1, 29); tf_round(x0, x1, 16); tf_round(x0, x1, 24);
  x0 += k2; x1 += k0 + 2u;
  tf_round(x0, x1, 13); tf_round(x0, x1, 15); tf_round(x0, x1, 26); tf_round(x0, x1, 6);
  x0 += k0; x1 += k1 + 3u;
  tf_round(x0, x1, 17); tf_round(x0, x1, 29); tf_round(x0, x1, 16); tf_round(x0, x1, 24);
  x0 += k1; x1 += k2 + 4u;
  tf_round(x0, x1, 13); tf_round(x0, x1, 15); tf_round(x0, x1, 26); tf_round(x0, x1, 6);
  x0 += k2; x1 += k0 + 5u;
  o0 = x0; o1 = x1;
}

__device__ __forceinline__ float tf_uniform(unsigned bits) {
  return __uint_as_float((bits >> 9) | 0x3F800000u) - 1.0f;
}

// ---------------------------------------------------------------- f32 -> bf16 (8 elems/thread)
__global__ __launch_bounds__(256) void conv_bf16(const float *__restrict__ src,
                                                 ushort *__restrict__ dst) {
  const size_t i = ((size_t)blockIdx.x * 256 + threadIdx.x) * 8;
  float4 a = *(const float4 *)(src + i);
  float4 b = *(const float4 *)(src + i + 4);
  uint4 o;
  o.x = (unsigned)f2bf(a.x) | ((unsigned)f2bf(a.y) << 16);
  o.y = (unsigned)f2bf(a.z) | ((unsigned)f2bf(a.w) << 16);
  o.z = (unsigned)f2bf(b.x) | ((unsigned)f2bf(b.y) << 16);
  o.w = (unsigned)f2bf(b.z) | ((unsigned)f2bf(b.w) << 16);
  *(uint4 *)(dst + i) = o;
}

// ---------------------------------------------------------------- enc -> ench + encT
__global__ __launch_bounds__(256) void conv_encT(const float *__restrict__ enc,
                                                 ushort *__restrict__ ench,
                                                 ushort *__restrict__ encT) {
  const int n = blockIdx.z;
  const int d0 = blockIdx.x * 32;
  const int k0 = blockIdx.y * 32;
  __shared__ ushort t[32][33];
  const int row = threadIdx.x >> 3;      // k within tile
  const int c4 = (threadIdx.x & 7) * 4;  // d within tile
  float4 v = *(const float4 *)(enc + ((size_t)n * TE + k0 + row) * DM + d0 + c4);
  ushort4 e;
  e.x = f2bf(v.x); e.y = f2bf(v.y); e.z = f2bf(v.z); e.w = f2bf(v.w);
  t[row][c4 + 0] = e.x; t[row][c4 + 1] = e.y;
  t[row][c4 + 2] = e.z; t[row][c4 + 3] = e.w;
  *(ushort4 *)(ench + ((size_t)n * TE + k0 + row) * DM + d0 + c4) = e;
  __syncthreads();
  const int dr = threadIdx.x >> 3;       // d within tile
  const int kc = (threadIdx.x & 7) * 4;  // k within tile
  ushort4 o;
  o.x = t[kc + 0][dr]; o.y = t[kc + 1][dr];
  o.z = t[kc + 2][dr]; o.w = t[kc + 3][dr];
  *(ushort4 *)(encT + ((size_t)n * DM + d0 + dr) * TE + k0 + kc) = o;
}

// ---------------------------------------------------------------- bf16 MFMA GEMM
// C[m][n] = scale * sum_k A[m][k]*B[n][k]   (both operands K-contiguous)
// 128x128 tile, 4 waves (2x2), each wave 4x4 16x16x32 MFMA tiles, BK=32.
// Staging via global_load_lds width=16 (m97 pattern).
__global__ __launch_bounds__(256) void gemm_bf16_mfma(
    const ushort *__restrict__ Ag, const ushort *__restrict__ Bg,
    float *__restrict__ Cg, int K, int N, size_t sA, size_t sB, size_t sC,
    float scale) {
  const int nb = blockIdx.z;
  const int n0 = blockIdx.x * 128;
  const int m0 = blockIdx.y * 128;
  const int tid = threadIdx.x;
  const int wave = tid >> 6, lane = tid & 63;
  const int wm = (wave >> 1) * 64, wn = (wave & 1) * 64;
  const int fr = lane & 15, quad = lane >> 4;
  const ushort *A = Ag + nb * sA + (size_t)m0 * K;
  const ushort *B = Bg + nb * sB + (size_t)n0 * K;
  __shared__ __align__(16) ushort As[128 * 32];
  __shared__ __align__(16) ushort Bs[128 * 32];
  f32x4 acc[4][4];
#pragma unroll
  for (int i = 0; i < 4; ++i)
#pragma unroll
    for (int c = 0; c < 4; ++c) acc[i][c] = (f32x4){0.f, 0.f, 0.f, 0.f};

  const int r0 = 32 * wave + (lane >> 2);  // global row this lane feeds
  const int c0 = (lane & 3) * 8;           // ushort chunk within the row
  const ushort *gA0 = A + (size_t)r0 * K + c0;
  const ushort *gA1 = A + (size_t)(r0 + 16) * K + c0;
  const ushort *gB0 = B + (size_t)r0 * K + c0;
  const ushort *gB1 = B + (size_t)(r0 + 16) * K + c0;
  ushort *lA0 = &As[(32 * wave) * 32];
  ushort *lA1 = &As[(32 * wave + 16) * 32];
  ushort *lB0 = &Bs[(32 * wave) * 32];
  ushort *lB1 = &Bs[(32 * wave + 16) * 32];

  for (int kb = 0; kb < K; kb += 32) {
    __syncthreads();  // prior compute finished reading LDS
    GLDS16(gA0 + kb, lA0);
    GLDS16(gA1 + kb, lA1);
    GLDS16(gB0 + kb, lB0);
    GLDS16(gB1 + kb, lB1);
    __syncthreads();  // compiler drains vmcnt before barrier -> data ready
    bf16x8 af[4], bfv[4];
#pragma unroll
    for (int i = 0; i < 4; ++i)
      af[i] = *(const bf16x8 *)(&As[(wm + i * 16 + fr) * 32 + quad * 8]);
#pragma unroll
    for (int c = 0; c < 4; ++c)
      bfv[c] = *(const bf16x8 *)(&Bs[(wn + c * 16 + fr) * 32 + quad * 8]);
#pragma unroll
    for (int i = 0; i < 4; ++i)
#pragma unroll
      for (int c = 0; c < 4; ++c)
        acc[i][c] = __builtin_amdgcn_mfma_f32_16x16x32_bf16(af[i], bfv[c],
                                                            acc[i][c], 0, 0, 0);
  }
  float *Cb = Cg + nb * sC;
#pragma unroll
  for (int i = 0; i < 4; ++i)
#pragma unroll
    for (int c = 0; c < 4; ++c)
#pragma unroll
      for (int r = 0; r < 4; ++r)
        Cb[(size_t)(m0 + wm + i * 16 + quad * 4 + r) * N + n0 + wn + c * 16 + fr] =
            acc[i][c][r] * scale;
}

// ---------------------------------------------------------------- cond_prob (parallel, T inline)
__global__ __launch_bounds__(256) void cond_prob2(
    const float *__restrict__ scores, float *__restrict__ cpT) {
  const int n = blockIdx.z;
  const int j0 = blockIdx.y * 64;
  const int k0 = blockIdx.x * 64;
  const int tid = threadIdx.x;
  __shared__ float eL[82][65];
  __shared__ float Tl[64];

  if (tid < 64) {
    unsigned o0, o1;
    threefry2x32(0u, (unsigned)(n * TE + k0 + tid), o0, o1);
    Tl[tid] = tf_uniform(o0 ^ o1) + 0.5f;  // T = u*(1.5-0.5)+0.5
  }
  __syncthreads();

  {
    const int c4 = (tid & 15) * 4;
    const int r0 = tid >> 4;  // 0..15
    const float it0 = 1.0f / Tl[c4 + 0], it1 = 1.0f / Tl[c4 + 1],
                it2 = 1.0f / Tl[c4 + 2], it3 = 1.0f / Tl[c4 + 3];
#pragma unroll
    for (int p = 0; p < 6; ++p) {
      const int r = r0 + p * 16;
      if (r < 82) {
        const int j = j0 + r;
        float4 s;
        if (j < TD) {
          s = *(const float4 *)(scores + ((size_t)n * TD + j) * TE + k0 + c4);
          s.x = __expf(s.x * it0); s.y = __expf(s.y * it1);
          s.z = __expf(s.z * it2); s.w = __expf(s.w * it3);
        } else {
          s = make_float4(0.f, 0.f, 0.f, 0.f);
        }
        eL[r][c4 + 0] = s.x; eL[r][c4 + 1] = s.y;
        eL[r][c4 + 2] = s.z; eL[r][c4 + 3] = s.w;
      }
    }
  }
  __syncthreads();

  const int k = tid & 63;
  const int jl0 = (tid >> 6) * 16;
  float e_r[35];
#pragma unroll
  for (int t = 0; t < 35; ++t) e_r[t] = eL[jl0 + t][k];
  float win = 0.f;
#pragma unroll
  for (int t = 15; t <= 33; ++t) win += e_r[t];
  float cp[16];
#pragma unroll
  for (int jl = 15; jl >= 0; --jl) {
    cp[jl] = e_r[jl] / (win + 1e-8f);
    if (jl > 0) win += e_r[jl - 1] - e_r[jl + 18];
  }
  float *dst = cpT + ((size_t)n * TE + k0 + k) * TD + j0 + jl0;
#pragma unroll
  for (int q = 0; q < 4; ++q)
    *(float4 *)(dst + q * 4) =
        make_float4(cp[q * 4], cp[q * 4 + 1], cp[q * 4 + 2], cp[q * 4 + 3]);
}

// ---------------------------------------------------------------- phase 1 scan + softmax (fused)
// Blocks 0..NB-1: DPP-exchange wave-synchronous scan (no LDS, no DS ops).
// Blocks NB..NB+NB*TD-1: one softmax row each (64 threads, no LDS).

#define P1_BODY(CU0, CU1, CU2, CU3, CL0, CL1, CL2, CL3, kk)                   \
  {                                                                           \
    /* prefetch cp column used at step (kk)+5 (column shift: col(k)=k-1) */   \
    const int pc = ((kk) + 4 < TE) ? ((kk) + 4) : (TE - 1);                   \
    const float *pp = cpn + (size_t)pc * TD + j0;                             \
    CL0 = *(const float4 *)(pp);                                              \
    CL1 = *(const float4 *)(pp + 4);                                          \
    CL2 = *(const float4 *)(pp + 8);                                          \
    CL3 = *(const float4 *)(pp + 12);                                         \
    const float q0 = a[0] * CU0.x, q1 = a[1] * CU0.y;                         \
    const float q2 = a[2] * CU0.z, q3 = a[3] * CU0.w;                         \
    const float q4 = a[4] * CU1.x, q5 = a[5] * CU1.y;                         \
    const float q6 = a[6] * CU1.z, q7 = a[7] * CU1.w;                         \
    const float q8 = a[8] * CU2.x, q9 = a[9] * CU2.y;                         \
    const float q10 = a[10] * CU2.z, q11 = a[11] * CU2.w;                     \
    const float q12 = a[12] * CU3.x, q13 = a[13] * CU3.y;                     \
    const float q14 = a[14] * CU3.z, q15 = a[15] * CU3.w;                     \
    /* halo via DPP: m_i = lane L-1's q_i ; p_i = lane L-2's q_{12+i} */      \
    const float m0 = DPP_SHR1(q0), m1 = DPP_SHR1(q1);                         \
    const float m2 = DPP_SHR1(q2), m3 = DPP_SHR1(q3);                         \
    const float m4 = DPP_SHR1(q4), m5 = DPP_SHR1(q5);                         \
    const float m6 = DPP_SHR1(q6), m7 = DPP_SHR1(q7);                         \
    const float m8 = DPP_SHR1(q8), m9 = DPP_SHR1(q9);                         \
    const float m10 = DPP_SHR1(q10), m11 = DPP_SHR1(q11);                     \
    const float m12 = DPP_SHR1(q12), m13 = DPP_SHR1(q13);                     \
    const float m14 = DPP_SHR1(q14), m15 = DPP_SHR1(q15);                     \
    const float p0 = DPP_SHR1(m12), p1 = DPP_SHR1(m13);                       \
    const float p2 = DPP_SHR1(m14), p3 = DPP_SHR1(m15);                       \
    float w[38];                                                              \
    w[4] = p0;   w[5] = p1;   w[6] = p2;   w[7] = p3;                         \
    w[8] = m0;   w[9] = m1;   w[10] = m2;  w[11] = m3;                        \
    w[12] = m4;  w[13] = m5;  w[14] = m6;  w[15] = m7;                        \
    w[16] = m8;  w[17] = m9;  w[18] = m10; w[19] = m11;                       \
    w[20] = m12; w[21] = m13; w[22] = m14; w[23] = m15;                       \
    w[24] = q0;  w[25] = q1;  w[26] = q2;  w[27] = q3;                        \
    w[28] = q4;  w[29] = q5;  w[30] = q6;  w[31] = q7;                        \
    w[32] = q8;  w[33] = q9;  w[34] = q10; w[35] = q11;                       \
    w[36] = q12; w[37] = q13;                                                 \
    /* window for j=j0+i is sum w[i+4 .. i+22]; two balanced trees + slides */\
    float t0 = w[4] + w[5], t1 = w[6] + w[7], t2 = w[8] + w[9];               \
    float t3 = w[10] + w[11], t4 = w[12] + w[13], t5 = w[14] + w[15];         \
    float t6 = w[16] + w[17], t7 = w[18] + w[19], t8 = w[20] + w[21];         \
    float s0 = (((t0 + t1) + (t2 + t3)) + ((t4 + t5) + (t6 + t7))) +          \
               (t8 + w[22]);                                                  \
    a[0] = s0;                                                                \
    s0 += w[23] - w[4];  a[1] = s0;                                           \
    s0 += w[24] - w[5];  a[2] = s0;                                           \
    s0 += w[25] - w[6];  a[3] = s0;                                           \
    s0 += w[26] - w[7];  a[4] = s0;                                           \
    s0 += w[27] - w[8];  a[5] = s0;                                           \
    s0 += w[28] - w[9];  a[6] = s0;                                           \
    s0 += w[29] - w[10]; a[7] = s0;                                           \
    float u4 = w[20] + w[21], u5 = w[22] + w[23], u6 = w[24] + w[25];         \
    float u7 = w[26] + w[27], u8 = w[28] + w[29];                             \
    float s1 = (((t4 + t5) + (t6 + t7)) + ((u4 + u5) + (u6 + u7))) +          \
               (u8 + w[30]);                                                  \
    a[8] = s1;                                                                \
    s1 += w[31] - w[12]; a[9] = s1;                                           \
    s1 += w[32] - w[13]; a[10] = s1;                                          \
    s1 += w[33] - w[14]; a[11] = s1;                                          \
    s1 += w[34] - w[15]; a[12] = s1;                                          \
    s1 += w[35] - w[16]; a[13] = s1;                                          \
    s1 += w[36] - w[17]; a[14] = s1;                                          \
    s1 += w[37] - w[18]; a[15] = s1;                                          \
    float *ao = an + (size_t)(kk)*TD + j0;                                    \
    *(float4 *)(ao) = make_float4(a[0], a[1], a[2], a[3]);                    \
    *(float4 *)(ao + 4) = make_float4(a[4], a[5], a[6], a[7]);                \
    *(float4 *)(ao + 8) = make_float4(a[8], a[9], a[10], a[11]);              \
    *(float4 *)(ao + 12) = make_float4(a[12], a[13], a[14], a[15]);           \
  }

__global__ __launch_bounds__(64) void phase1_softmax(
    const float *__restrict__ cpT, float *__restrict__ aT,
    const float *__restrict__ scores, float *__restrict__ out1) {
  if (blockIdx.x >= NB) {
    // ---------------- softmax row (64 threads, float2 path) ----------------
    const int row = blockIdx.x - NB;  // n*TD + j
    const int n = row >> 10;
    const int j = row & 1023;
    const int tid = threadIdx.x;
    const float2 *s2 = (const float2 *)(scores + (size_t)row * TE);
    float2 a0 = s2[tid], a1 = s2[tid + 64], a2 = s2[tid + 128];
    float m = fmaxf(fmaxf(fmaxf(a0.x, a0.y), fmaxf(a1.x, a1.y)),
                    fmaxf(a2.x, a2.y));
#pragma unroll
    for (int off = 32; off; off >>= 1) m = fmaxf(m, __shfl_xor(m, off));
    float e0 = __expf(a0.x - m), e1 = __expf(a0.y - m);
    float e2 = __expf(a1.x - m), e3 = __expf(a1.y - m);
    float e4 = __expf(a2.x - m), e5 = __expf(a2.y - m);
    float sum = ((e0 + e1) + (e2 + e3)) + (e4 + e5);
#pragma unroll
    for (int off = 32; off; off >>= 1) sum += __shfl_xor(sum, off);
    const float r = 1.0f / sum;
    float2 *d2 = (float2 *)(out1 + (size_t)n * (2 * TD * TE) + (size_t)j * TE);
    d2[tid] = make_float2(e0 * r, e1 * r);
    d2[tid + 64] = make_float2(e2 * r, e3 * r);
    d2[tid + 128] = make_float2(e4 * r, e5 * r);
    return;
  }

  // ------------------------- phase-1 scan (1 wave) -------------------------
  const int n = blockIdx.x;
  const int L = threadIdx.x;  // 0..63, one wave
  const int j0 = L * 16;

  const float *cpn = cpT + (size_t)n * TE * TD;
  float *an = aT + (size_t)n * TE * TD;

  float a[16];
#pragma unroll
  for (int i = 0; i < 16; ++i) a[i] = 0.f;
  if (L == 0) a[0] = 1.f;

  // prologue: step s uses column max(s-1,0); fill sets for steps 0..4
  float4 cpA0, cpA1, cpA2, cpA3, cpB0, cpB1, cpB2, cpB3;
  float4 cpC0, cpC1, cpC2, cpC3, cpD0, cpD1, cpD2, cpD3;
  float4 cpE0, cpE1, cpE2, cpE3, cpF0, cpF1, cpF2, cpF3;
  {
    const float *p0 = cpn + j0;  // col 0 (steps 0 and 1)
    cpA0 = *(const float4 *)(p0);
    cpA1 = *(const float4 *)(p0 + 4);
    cpA2 = *(const float4 *)(p0 + 8);
    cpA3 = *(const float4 *)(p0 + 12);
    cpB0 = cpA0; cpB1 = cpA1; cpB2 = cpA2; cpB3 = cpA3;
    const float *p1 = cpn + (size_t)1 * TD + j0;  // col 1 (step 2)
    cpC0 = *(const float4 *)(p1);
    cpC1 = *(const float4 *)(p1 + 4);
    cpC2 = *(const float4 *)(p1 + 8);
    cpC3 = *(const float4 *)(p1 + 12);
    const float *p2 = cpn + (size_t)2 * TD + j0;  // col 2 (step 3)
    cpD0 = *(const float4 *)(p2);
    cpD1 = *(const float4 *)(p2 + 4);
    cpD2 = *(const float4 *)(p2 + 8);
    cpD3 = *(const float4 *)(p2 + 12);
    const float *p3 = cpn + (size_t)3 * TD + j0;  // col 3 (step 4)
    cpE0 = *(const float4 *)(p3);
    cpE1 = *(const float4 *)(p3 + 4);
    cpE2 = *(const float4 *)(p3 + 8);
    cpE3 = *(const float4 *)(p3 + 12);
  }

  for (int k = 0; k < TE; k += 6) {  // TE = 384 = 6*64
    P1_BODY(cpA0, cpA1, cpA2, cpA3, cpF0, cpF1, cpF2, cpF3, k);
    P1_BODY(cpB0, cpB1, cpB2, cpB3, cpA0, cpA1, cpA2, cpA3, k + 1);
    P1_BODY(cpC0, cpC1, cpC2, cpC3, cpB0, cpB1, cpB2, cpB3, k + 2);
    P1_BODY(cpD0, cpD1, cpD2, cpD3, cpC0, cpC1, cpC2, cpC3, k + 3);
    P1_BODY(cpE0, cpE1, cpE2, cpE3, cpD0, cpD1, cpD2, cpD3, k + 4);
    P1_BODY(cpF0, cpF1, cpF2, cpF3, cpE0, cpE1, cpE2, cpE3, k + 5);
  }
}

// ---------------------------------------------------------------- phase 2 + transpose (merged)
// Tile: 64 k x 64 j per block, 256 threads. Computes B[j,k] from aT/cpT
// (k-major, coalesced loads) and writes BOTH final layouts directly:
// out1 f32 [n][1][j][k] and Bh bf16 [n][j][k]. Inner d-loop identical to
// the old phase2_B. Boundary semantics: a[j<0]=0, cp[j>1023]=0, cp[1023]=0.
#define P2_LDW 85  // odd stride -> conflict-free across k-lanes

__global__ __launch_bounds__(256) void phase2t(
    const float *__restrict__ cpT, const float *__restrict__ aT,
    float *__restrict__ out1, ushort *__restrict__ Bh) {
  const int k0 = blockIdx.x * 64;
  const int j0 = blockIdx.y * 64;
  const int n = blockIdx.z;
  const int tid = threadIdx.x;

  __shared__ float aL[64 * P2_LDW];   // col c <-> global j = j0 - 20 + c
  __shared__ float cpL[64 * P2_LDW];  // col c <-> global j = j0 + c

  // ---- load: 4 lanes per k-row, float4 columns (21 per array) ----
  {
    const int r = tid >> 2;  // k row 0..63
    const float *arow = aT + ((size_t)n * TE + k0 + r) * TD;
    const float *crow = cpT + ((size_t)n * TE + k0 + r) * TD;
    for (int c = (tid & 3); c < 21; c += 4) {
      const int aj = j0 - 20 + 4 * c;  // multiples of 4; fully <0 or >=0
      float4 av = (aj >= 0) ? *(const float4 *)(arow + aj)
                            : make_float4(0.f, 0.f, 0.f, 0.f);
      *(float4 *)(&aL[r * P2_LDW + 4 * c]) = av;
      const int cj = j0 + 4 * c;
      float4 cv;
      if (cj + 3 <= TD - 1) {
        cv = *(const float4 *)(crow + cj);
        if (cj + 3 == TD - 1) cv.w = 0.f;  // cp[1023] never contributes
      } else {
        cv = make_float4(0.f, 0.f, 0.f, 0.f);
      }
      *(float4 *)(&cpL[r * P2_LDW + 4 * c]) = cv;
    }
  }
  __syncthreads();

  // ---- compute: thread = (k_r, jg); 16 outputs in 4 chunks of 4 j ----
  const int k_r = tid & 63;
  const int jg = tid >> 6;  // 0..3 (wave index)
  const float *aRow = &aL[k_r * P2_LDW];
  const float *cRow = &cpL[k_r * P2_LDW];
  float Bo[4][4];
#pragma unroll
  for (int cc = 0; cc < 4; ++cc) {
    const int jl = jg * 16 + cc * 4;  // local j of first output in chunk
    float ar[21], cpr[21];
#pragma unroll
    for (int t = 0; t < 21; ++t) ar[t] = aRow[jl + 1 + t];   // a[j-19+t]
#pragma unroll
    for (int t = 0; t < 21; ++t) cpr[t] = cRow[jl + t];      // cp[j+t]
#pragma unroll
    for (int i = 0; i < 4; ++i) {
      float W = 0.f, acc2 = 0.f;
#pragma unroll
      for (int d = 19; d >= 2; --d) {
        W += cpr[i + 19 - d];
        acc2 = fmaf(ar[19 + i - d], W, acc2);
      }
      Bo[cc][i] = acc2;
    }
  }
  __syncthreads();  // aL free now

  // ---- stage B tile [64j][65] in LDS, then write both layouts ----
  float *Btile = aL;  // 64*65 = 4160 floats <= 64*85
#pragma unroll
  for (int cc = 0; cc < 4; ++cc)
#pragma unroll
    for (int i = 0; i < 4; ++i)
      Btile[(jg * 16 + cc * 4 + i) * 65 + k_r] = Bo[cc][i];
  __syncthreads();

  {
    const int jr = tid >> 2;  // j row 0..63
    const int c = tid & 3;
    float *orow = out1 + (size_t)n * (2 * TD * TE) + (size_t)TD * TE +
                  (size_t)(j0 + jr) * TE + k0;
    ushort *hrow = Bh + ((size_t)n * TD + j0 + jr) * TE + k0;
#pragma unroll
    for (int q = 0; q < 4; ++q) {
      const int f = c + q * 4;  // float4 index 0..15 within the row
      float4 v = make_float4(Btile[jr * 65 + 4 * f + 0],
                             Btile[jr * 65 + 4 * f + 1],
                             Btile[jr * 65 + 4 * f + 2],
                             Btile[jr * 65 + 4 * f + 3]);
      *(float4 *)(orow + 4 * f) = v;
      ushort4 h;
      h.x = f2bf(v.x); h.y = f2bf(v.y); h.z = f2bf(v.z); h.w = f2bf(v.w);
      *(ushort4 *)(hrow + 4 * f) = h;
    }
  }
}

// ---------------------------------------------------------------- launch
extern "C" void kernel_launch(void *const *d_in, const int *in_sizes, int n_in,
                              void *d_out, int out_size, void *d_ws,
                              size_t ws_size, hipStream_t stream) {
  (void)in_sizes; (void)n_in; (void)out_size; (void)ws_size;
  const float *enc = (const float *)d_in[0];  // [32][384][512]
  const float *mel = (const float *)d_in[1];  // [32][1024][512]
  float *out = (float *)d_out;
  float *out0 = out;                         // att_out [32][1024][512]
  float *out1 = out + (size_t)NB * TD * DM;  // stacked [32][2][1024][384]

  const size_t SZ = (size_t)NB * TD * TE;    // 12,582,912 floats
  float *ws = (float *)d_ws;
  float *ws_scores = ws;       // scores [n][j][k]; later Bh (bf16)
  float *ws_cpT = ws + SZ;     // cond_prob [n][k][j] (holds ench+melh before)
  float *ws_aT = ws + 2 * SZ;  // a [n][k][j]
  ushort *encTb = (ushort *)(ws + 3 * SZ + NB * TE);  // encT bf16 [n][d][k]
  ushort *ench = (ushort *)ws_cpT;                    // bf16 [n][k][d]
  ushort *melh = (ushort *)ws_cpT + (size_t)NB * TE * DM;  // bf16 [n][j][d]
  ushort *Bh = (ushort *)ws_scores;  // bf16 [n][j][k] (scores dead by then)

  conv_bf16<<<(NB * TD * DM) / (256 * 8), 256, 0, stream>>>(mel, melh);
  conv_encT<<<dim3(DM / 32, TE / 32, NB), 256, 0, stream>>>(enc, ench, encTb);
  gemm_bf16_mfma<<<dim3(TE / 128, TD / 128, NB), 256, 0, stream>>>(
      melh, ench, ws_scores, DM, TE, (size_t)TD * DM, (size_t)TE * DM,
      (size_t)TD * TE, 0.0441941738241592f);
  cond_prob2<<<dim3(TE / 64, TD / 64, NB), 256, 0, stream>>>(ws_scores, ws_cpT);
  phase1_softmax<<<NB + NB * TD, 64, 0, stream>>>(ws_cpT, ws_aT, ws_scores,
                                                  out1);
  phase2t<<<dim3(TE / 64, TD / 64, NB), 256, 0, stream>>>(ws_cpT, ws_aT, out1,
                                                          Bh);
  gemm_bf16_mfma<<<dim3(DM / 128, TD / 128, NB), 256, 0, stream>>>(
      Bh, encTb, out0, TE, DM, (size_t)TD * TE, (size_t)DM * TE,
      (size_t)TD * DM, 1.0f);
}